// Round 2
// baseline (378.975 us; speedup 1.0000x reference)
//
#include <hip/hip_runtime.h>

typedef unsigned short u16;
typedef unsigned int u32;
typedef float f32x4 __attribute__((ext_vector_type(4)));
typedef __bf16 bf16x8 __attribute__((ext_vector_type(8)));

#define T_TOK 4096
#define HDIM 1024
#define IDIM 512
#define NEXP 32
#define KSEL 8
#define CAPE 2048
#define NROW (NEXP*CAPE + T_TOK)   // 69632 rows total (experts + shared)

__device__ __forceinline__ u16 f32_to_bf16(float f) {
  u32 x = __float_as_uint(f);
  u32 r = (x + 0x7FFFu + ((x >> 16) & 1u)) >> 16;   // RNE; inputs finite
  return (u16)r;
}
__device__ __forceinline__ float bf16_to_f32(u16 u) {
  return __uint_as_float(((u32)u) << 16);
}

// ---------------- fp32 -> bf16 plain convert (n8 = count of 8-elem chunks) ----------------
__global__ __launch_bounds__(256) void k_cvt(const float* __restrict__ src, u16* __restrict__ dst, long n8) {
  long i = blockIdx.x * 256L + threadIdx.x;
  long stride = (long)gridDim.x * 256L;
  for (long j = i; j < n8; j += stride) {
    float4 a = reinterpret_cast<const float4*>(src)[2*j];
    float4 b = reinterpret_cast<const float4*>(src)[2*j+1];
    ushort4 lo, hi;
    lo.x=f32_to_bf16(a.x); lo.y=f32_to_bf16(a.y); lo.z=f32_to_bf16(a.z); lo.w=f32_to_bf16(a.w);
    hi.x=f32_to_bf16(b.x); hi.y=f32_to_bf16(b.y); hi.z=f32_to_bf16(b.z); hi.w=f32_to_bf16(b.w);
    reinterpret_cast<ushort4*>(dst)[2*j]   = lo;
    reinterpret_cast<ushort4*>(dst)[2*j+1] = hi;
  }
}

// ---------------- w13 convert with 16-row w1/w3 interleave ----------------
__global__ __launch_bounds__(256) void k_cvt_w13(const float* __restrict__ src1, const float* __restrict__ src3,
                                                 u16* __restrict__ dst, int nexp, long sstride) {
  long n8 = (long)nexp * 1024 * 128;
  long i = blockIdx.x * 256L + threadIdx.x;
  long stride = (long)gridDim.x * 256L;
  for (long j = i; j < n8; j += stride) {
    int e   = (int)(j >> 17);
    int rem = (int)(j & 131071);
    int rowd = rem >> 7;
    int c8   = rem & 127;
    int c = rowd >> 4, cw = rowd & 15;
    int srow = (c >> 1) * 16 + cw;
    const float* s = ((c & 1) ? src3 : src1) + (long)e * sstride + (long)srow * HDIM + c8 * 8;
    float4 a = reinterpret_cast<const float4*>(s)[0];
    float4 b = reinterpret_cast<const float4*>(s)[1];
    ushort4 lo, hi;
    lo.x=f32_to_bf16(a.x); lo.y=f32_to_bf16(a.y); lo.z=f32_to_bf16(a.z); lo.w=f32_to_bf16(a.w);
    hi.x=f32_to_bf16(b.x); hi.y=f32_to_bf16(b.y); hi.z=f32_to_bf16(b.z); hi.w=f32_to_bf16(b.w);
    u16* d = dst + ((long)e * 1024 + rowd) * HDIM + c8 * 8;
    reinterpret_cast<ushort4*>(d)[0] = lo;
    reinterpret_cast<ushort4*>(d)[1] = hi;
  }
}

// ---------------- gating: fp64 scores + group-limited top-k ----------------
__global__ __launch_bounds__(256) void k_gate(const float* __restrict__ x, const float* __restrict__ gw,
                                              int* __restrict__ idx, float* __restrict__ wts) {
  __shared__ float xs[32][129];
  __shared__ float gs_[32][129];
  __shared__ double sc[32][32];
  const int tid = threadIdx.x;
  const int t0 = blockIdx.x * 32;
  const int tl = tid & 31, g = tid >> 5;
  double acc0 = 0, acc1 = 0, acc2 = 0, acc3 = 0;
  for (int k0 = 0; k0 < HDIM; k0 += 128) {
#pragma unroll
    for (int q = 0; q < 4; ++q) {
      int f = tid + 256 * q;
      int row = f >> 5, c4 = (f & 31) * 4;
      float4 v = *reinterpret_cast<const float4*>(x + (long)(t0 + row) * HDIM + k0 + c4);
      xs[row][c4+0]=v.x; xs[row][c4+1]=v.y; xs[row][c4+2]=v.z; xs[row][c4+3]=v.w;
      float4 w = *reinterpret_cast<const float4*>(gw + (long)row * HDIM + k0 + c4);
      gs_[row][c4+0]=w.x; gs_[row][c4+1]=w.y; gs_[row][c4+2]=w.z; gs_[row][c4+3]=w.w;
    }
    __syncthreads();
#pragma unroll 4
    for (int kk = 0; kk < 128; ++kk) {
      double xv = (double)xs[tl][kk];
      acc0 += xv * (double)gs_[g     ][kk];
      acc1 += xv * (double)gs_[g +  8][kk];
      acc2 += xv * (double)gs_[g + 16][kk];
      acc3 += xv * (double)gs_[g + 24][kk];
    }
    __syncthreads();
  }
  sc[tl][g     ] = 1.0 / (1.0 + exp(-acc0));
  sc[tl][g +  8] = 1.0 / (1.0 + exp(-acc1));
  sc[tl][g + 16] = 1.0 / (1.0 + exp(-acc2));
  sc[tl][g + 24] = 1.0 / (1.0 + exp(-acc3));
  __syncthreads();
  if (tid < 32) {
    int t = t0 + tid;
    double gsc[8];
#pragma unroll
    for (int gg = 0; gg < 8; ++gg) {
      double mx = sc[tid][4*gg];
#pragma unroll
      for (int j = 1; j < 4; ++j) mx = fmax(mx, sc[tid][4*gg + j]);
      gsc[gg] = mx;
    }
    unsigned gmask = 0;
    for (int it = 0; it < 4; ++it) {
      double best = -1e300; int bi = 0;
      for (int gg = 0; gg < 8; ++gg)
        if (!((gmask >> gg) & 1) && gsc[gg] > best) { best = gsc[gg]; bi = gg; }
      gmask |= 1u << bi;
    }
    unsigned emask = 0; int ei[KSEL]; double ew[KSEL]; double wsum = 0;
    for (int it = 0; it < KSEL; ++it) {
      double best = -1e300; int bi = 0;
      for (int e = 0; e < NEXP; ++e)
        if (((gmask >> (e >> 2)) & 1) && !((emask >> e) & 1)) {
          double v = sc[tid][e];
          if (v > best) { best = v; bi = e; }
        }
      emask |= 1u << bi; ei[it] = bi; ew[it] = best; wsum += best;
    }
    double s = 2.5 / (wsum + 1e-20);
    for (int k = 0; k < KSEL; ++k) { idx[t*KSEL + k] = ei[k]; wts[t*KSEL + k] = (float)(ew[k] * s); }
  }
}

// ---------------- capacity assignment: per-expert ordered scan ----------------
__global__ __launch_bounds__(256) void k_assign(const int* __restrict__ idx,
                                                int* __restrict__ etok, int* __restrict__ pos,
                                                int* __restrict__ cnts) {
  const int e = blockIdx.x;
  const int tid = threadIdx.x;
  if (e == NEXP) {
    for (int t = tid; t < T_TOK; t += 256) etok[NEXP*CAPE + t] = t;
    if (tid == 0) cnts[NEXP] = T_TOK;
    return;
  }
  __shared__ int scan[256];
  int base = 0;
  for (int t0 = 0; t0 < T_TOK; t0 += 256) {
    int t = t0 + tid;
    int found = -1;
#pragma unroll
    for (int k = 0; k < KSEL; ++k) if (idx[t*KSEL + k] == e) found = k;
    int flag = (found >= 0) ? 1 : 0;
    __syncthreads();
    scan[tid] = flag;
    __syncthreads();
    for (int off = 1; off < 256; off <<= 1) {
      int v = scan[tid];
      int add = (tid >= off) ? scan[tid - off] : 0;
      __syncthreads();
      scan[tid] = v + add;
      __syncthreads();
    }
    int incl = scan[tid];
    int total = scan[255];
    if (flag) {
      int slot = base + incl - 1;
      pos[t*KSEL + found] = slot;
      if (slot < CAPE) etok[e*CAPE + slot] = t;
    }
    base += total;
  }
  if (tid == 0) cnts[e] = min(base, CAPE);
}

// ---------------- grouped GEMM: 256x256 tile, BK=64, 8-phase counted-vmcnt schedule ----------------
// T1 XCD swizzle + T2 XOR LDS swizzle + T3/T4 8-phase counted vmcnt + T5 setprio.
// Wave (wm,wn): wm in {0,1}, wn in {0..3}. Interleaved mapping so quadrant phase = global half:
//   A row  = mq*128 + wm*64 + m*16 + (lane&15),  m in 0..3
//   B row  = nq*128 + wn*32 + n*16 + (lane&15),  n in 0..1
// Phase order (mq,nq): q0=(0,0) q1=(0,1) q2=(1,1) q3=(1,0); B0 frags held in regs q0->q3.
// Stage slots: q0 -> A1(t+1), q1 -> B0(t+2), q2 -> A0(t+2), q3 -> B1(t+2); vmcnt(6) at each
// K-tile boundary  (= 3 half-tiles in flight; every half of tile t+1 landed at its boundary).

#define GLDS(gp, lp) __builtin_amdgcn_global_load_lds( \
    (const __attribute__((address_space(1))) void*)(gp), \
    (__attribute__((address_space(3))) void*)(lp), 16, 0, 0)

template<int KDIM, bool GATHER, bool ACT>
__global__ __launch_bounds__(512, 2) void k_gemm8(const u16* __restrict__ A, const u16* __restrict__ Ball,
                                                  u16* __restrict__ out,
                                                  const int* __restrict__ etok, const int* __restrict__ cnts) {
  constexpr int NT = KDIM / 64;
  constexpr int MSK = NT - 1;
  __shared__ u16 lds[65536];            // [dbuf 2][op 2][256*64], 128 KiB

  // T1: bijective XCD swizzle over flattened grid (2112 = 8*264 blocks)
  int bid0 = blockIdx.x;
  int bid = (bid0 & 7) * 264 + (bid0 >> 3);
  int xt = bid & 3, yt = (bid >> 2) & 15, e = bid >> 6;

  const int cnt = cnts[e];
  const int brow = yt * 256;
  if (brow >= cnt) return;
  const int rv = min(256, cnt - brow);
  const long rowbase = (long)e * CAPE;
  const u16* Bexp = Ball + (size_t)e * (size_t)(1024 * KDIM);

  const int tid = threadIdx.x;
  const int wave = tid >> 6, lane = tid & 63;
  const int wm = wave >> 2, wn = wave & 3;
  const int lr = lane & 15;
  const int lk = (lane >> 4) * 16;      // byte offset of this lane's K-slot

  // staging source pointers: sub-issue j covers tile rows j*64..j*64+63
  const u16* pa[4]; const u16* pb[4];
#pragma unroll
  for (int j = 0; j < 4; ++j) {
    int row = j*64 + (tid >> 3);
    int sl = (tid & 7) ^ (row & 7);                  // pre-swizzled source chunk
    long arow;
    if (GATHER) arow = (row < rv) ? (long)etok[rowbase + brow + row] : 0L;
    else        arow = rowbase + brow + row;
    pa[j] = A + arow * KDIM + sl * 8;
    pb[j] = Bexp + ((long)(xt*256 + row)) * KDIM + sl * 8;
  }

  // stage half h (0: rows 0-127, 1: rows 128-255) of operand o of K-tile st (pre-masked)
  auto STAGE = [&](int st, int o, int h) {
    int dbase = (st & 1) * 32768 + o * 16384;
    const u16* const* pp = o ? pb : pa;
#pragma unroll
    for (int s = 0; s < 2; ++s) {
      int j = h*2 + s;
      GLDS(pp[j] + st * 64, &lds[dbase + j*4096 + wave*512]);
    }
  };

  const char* ldsb = (const char*)lds;
  auto RD = [&](int d, int o, int r, int kk) -> bf16x8 {
    int bc = (kk*64 + lk) ^ ((r & 7) << 4);
    return *(const bf16x8*)(ldsb + (size_t)(d*65536 + o*32768 + r*128 + bc));
  };

  f32x4 acc[8][4];
#pragma unroll
  for (int m = 0; m < 8; ++m)
#pragma unroll
    for (int n = 0; n < 4; ++n) acc[m][n] = (f32x4){0.f,0.f,0.f,0.f};

  // prologue: tile0 fully, tile1 {A0,B0,B1}; A1(1) staged at t=0.q0
  STAGE(0,0,0); STAGE(0,1,0); STAGE(0,0,1); STAGE(0,1,1);
  STAGE(1,0,0); STAGE(1,1,0); STAGE(1,1,1);
  asm volatile("s_waitcnt vmcnt(6)" ::: "memory");    // tile0's 8 loads landed
  __builtin_amdgcn_sched_barrier(0);
  __builtin_amdgcn_s_barrier();

  bf16x8 a[4][2], b[2][2], b0h[2][2];

  for (int t = 0; t < NT; ++t) {
    const int d = t & 1;
    // ---------- q0: (mq=0, nq=0) — read A0(8) + B0(4); stage A1(t+1) ----------
#pragma unroll
    for (int m = 0; m < 4; ++m)
#pragma unroll
      for (int kk = 0; kk < 2; ++kk) a[m][kk] = RD(d, 0, wm*64 + m*16 + lr, kk);
#pragma unroll
    for (int n = 0; n < 2; ++n)
#pragma unroll
      for (int kk = 0; kk < 2; ++kk) { b[n][kk] = RD(d, 1, wn*32 + n*16 + lr, kk); b0h[n][kk] = b[n][kk]; }
    STAGE((t+1) & MSK, 0, 1);
    __builtin_amdgcn_s_barrier();
    asm volatile("s_waitcnt lgkmcnt(0)" ::: "memory");
    __builtin_amdgcn_sched_barrier(0);
    __builtin_amdgcn_s_setprio(1);
#pragma unroll
    for (int m = 0; m < 4; ++m)
#pragma unroll
      for (int n = 0; n < 2; ++n)
#pragma unroll
        for (int kk = 0; kk < 2; ++kk)
          acc[m][n] = __builtin_amdgcn_mfma_f32_16x16x32_bf16(a[m][kk], b[n][kk], acc[m][n], 0, 0, 0);
    __builtin_amdgcn_s_setprio(0);
    __builtin_amdgcn_sched_barrier(0);
    __builtin_amdgcn_s_barrier();
    // ---------- q1: (mq=0, nq=1) — read B1(4); stage B0(t+2) ----------
#pragma unroll
    for (int n = 0; n < 2; ++n)
#pragma unroll
      for (int kk = 0; kk < 2; ++kk) b[n][kk] = RD(d, 1, 128 + wn*32 + n*16 + lr, kk);
    STAGE((t+2) & MSK, 1, 0);
    __builtin_amdgcn_s_barrier();
    asm volatile("s_waitcnt lgkmcnt(0)" ::: "memory");
    __builtin_amdgcn_sched_barrier(0);
    __builtin_amdgcn_s_setprio(1);
#pragma unroll
    for (int m = 0; m < 4; ++m)
#pragma unroll
      for (int n = 0; n < 2; ++n)
#pragma unroll
        for (int kk = 0; kk < 2; ++kk)
          acc[m][2+n] = __builtin_amdgcn_mfma_f32_16x16x32_bf16(a[m][kk], b[n][kk], acc[m][2+n], 0, 0, 0);
    __builtin_amdgcn_s_setprio(0);
    __builtin_amdgcn_sched_barrier(0);
    __builtin_amdgcn_s_barrier();
    // ---------- q2: (mq=1, nq=1) — read A1(8); stage A0(t+2) ----------
#pragma unroll
    for (int m = 0; m < 4; ++m)
#pragma unroll
      for (int kk = 0; kk < 2; ++kk) a[m][kk] = RD(d, 0, 128 + wm*64 + m*16 + lr, kk);
    STAGE((t+2) & MSK, 0, 0);
    __builtin_amdgcn_s_barrier();
    asm volatile("s_waitcnt lgkmcnt(0)" ::: "memory");
    __builtin_amdgcn_sched_barrier(0);
    __builtin_amdgcn_s_setprio(1);
#pragma unroll
    for (int m = 0; m < 4; ++m)
#pragma unroll
      for (int n = 0; n < 2; ++n)
#pragma unroll
        for (int kk = 0; kk < 2; ++kk)
          acc[4+m][2+n] = __builtin_amdgcn_mfma_f32_16x16x32_bf16(a[m][kk], b[n][kk], acc[4+m][2+n], 0, 0, 0);
    __builtin_amdgcn_s_setprio(0);
    __builtin_amdgcn_sched_barrier(0);
    __builtin_amdgcn_s_barrier();
    // ---------- q3: (mq=1, nq=0) — no ds_reads (A1 + held B0); stage B1(t+2) ----------
    STAGE((t+2) & MSK, 1, 1);
    __builtin_amdgcn_s_barrier();
    asm volatile("s_waitcnt lgkmcnt(0)" ::: "memory");
    __builtin_amdgcn_sched_barrier(0);
    __builtin_amdgcn_s_setprio(1);
#pragma unroll
    for (int m = 0; m < 4; ++m)
#pragma unroll
      for (int n = 0; n < 2; ++n)
#pragma unroll
        for (int kk = 0; kk < 2; ++kk)
          acc[4+m][n] = __builtin_amdgcn_mfma_f32_16x16x32_bf16(a[m][kk], b0h[n][kk], acc[4+m][n], 0, 0, 0);
    __builtin_amdgcn_s_setprio(0);
    __builtin_amdgcn_sched_barrier(0);
    asm volatile("s_waitcnt vmcnt(6)" ::: "memory");    // K-tile boundary: tile t+1 fully landed
    __builtin_amdgcn_s_barrier();
  }

  // epilogue: C/D map col=lane&15, row=(lane>>4)*4+reg  [verified m89]
  const int rl = (lane >> 4) << 2;
  if (ACT) {
#pragma unroll
    for (int mq = 0; mq < 2; ++mq)
#pragma unroll
      for (int m = 0; m < 4; ++m) {
        int rbase = mq*128 + wm*64 + m*16 + rl;
#pragma unroll
        for (int nq = 0; nq < 2; ++nq) {
          f32x4 h1 = acc[mq*4+m][nq*2], h3 = acc[mq*4+m][nq*2+1];
          int ucol = xt*128 + nq*64 + wn*16 + lr;
#pragma unroll
          for (int j = 0; j < 4; ++j) {
            int lrow = rbase + j;
            if (lrow < rv) {
              float v1 = h1[j];
              float uu = v1 / (1.f + __expf(-v1)) * h3[j];   // silu(h1)*h3
              out[(size_t)(rowbase + brow + lrow) * IDIM + ucol] = f32_to_bf16(uu);
            }
          }
        }
      }
  } else {
#pragma unroll
    for (int mq = 0; mq < 2; ++mq)
#pragma unroll
      for (int m = 0; m < 4; ++m) {
        int rbase = mq*128 + wm*64 + m*16 + rl;
#pragma unroll
        for (int nq = 0; nq < 2; ++nq)
#pragma unroll
          for (int n = 0; n < 2; ++n) {
            int col = xt*256 + nq*128 + wn*32 + n*16 + lr;
            f32x4 v = acc[mq*4+m][nq*2+n];
#pragma unroll
            for (int j = 0; j < 4; ++j) {
              int lrow = rbase + j;
              if (lrow < rv)
                out[(size_t)(rowbase + brow + lrow) * HDIM + col] = f32_to_bf16(v[j]);
            }
          }
      }
  }
}

// ---------------- combine: y[t] = sum_k w_k * oe[e_k][pos_k] + shared[t] ----------------
__global__ __launch_bounds__(256) void k_combine(const u16* __restrict__ oe,
                                                 const int* __restrict__ idx, const float* __restrict__ wts,
                                                 const int* __restrict__ pos, float* __restrict__ y) {
  int t = blockIdx.x;
  int h0 = threadIdx.x * 4;
  float a0 = 0, a1 = 0, a2 = 0, a3 = 0;
#pragma unroll
  for (int k = 0; k < KSEL; ++k) {
    int e = idx[t*KSEL + k];
    int p = pos[t*KSEL + k];
    if (p < CAPE) {
      float w = wts[t*KSEL + k];
      ushort4 v = *reinterpret_cast<const ushort4*>(oe + ((long)e * CAPE + p) * HDIM + h0);
      a0 += w * bf16_to_f32(v.x); a1 += w * bf16_to_f32(v.y);
      a2 += w * bf16_to_f32(v.z); a3 += w * bf16_to_f32(v.w);
    }
  }
  ushort4 s = *reinterpret_cast<const ushort4*>(oe + ((long)NEXP * CAPE + t) * HDIM + h0);
  a0 += bf16_to_f32(s.x); a1 += bf16_to_f32(s.y); a2 += bf16_to_f32(s.z); a3 += bf16_to_f32(s.w);
  float4 o; o.x = a0; o.y = a1; o.z = a2; o.w = a3;
  reinterpret_cast<float4*>(y + (long)t * HDIM)[threadIdx.x] = o;
}

extern "C" void kernel_launch(void* const* d_in, const int* in_sizes, int n_in,
                              void* d_out, int out_size, void* d_ws, size_t ws_size,
                              hipStream_t stream) {
  const float* x      = (const float*)d_in[0];
  const float* gate_w = (const float*)d_in[1];
  const float* w13    = (const float*)d_in[2];
  const float* w2     = (const float*)d_in[3];
  const float* sw1    = (const float*)d_in[4];
  const float* sw2    = (const float*)d_in[5];
  const float* sw3    = (const float*)d_in[6];
  float* y = (float*)d_out;

  char* base = (char*)d_ws;
  size_t off = 0;
  auto alloc = [&](size_t bytes) -> void* {
    void* p = base + off;
    off = (off + bytes + 255) & ~(size_t)255;
    return p;
  };
  u16* xb    = (u16*)alloc((size_t)T_TOK * HDIM * 2);
  u16* w13b  = (u16*)alloc((size_t)(NEXP + 1) * 2 * IDIM * HDIM * 2);
  u16* w2b   = (u16*)alloc((size_t)(NEXP + 1) * HDIM * IDIM * 2);
  u16* u_ws  = (u16*)alloc((size_t)NROW * IDIM * 2);
  u16* oe_ws = (u16*)alloc((size_t)NROW * HDIM * 2);
  int*   idx  = (int*)alloc((size_t)T_TOK * KSEL * 4);
  float* wts  = (float*)alloc((size_t)T_TOK * KSEL * 4);
  int*   pos  = (int*)alloc((size_t)T_TOK * KSEL * 4);
  int*   etok = (int*)alloc((size_t)NROW * 4);
  int*   cnts = (int*)alloc(256);
  if (off > ws_size) return;

  k_cvt<<<dim3(2048), dim3(256), 0, stream>>>(x, xb, (long)T_TOK * HDIM / 8);
  k_cvt<<<dim3(2048), dim3(256), 0, stream>>>(w2, w2b, (long)NEXP * HDIM * IDIM / 8);
  k_cvt<<<dim3(256),  dim3(256), 0, stream>>>(sw2, w2b + (size_t)NEXP * HDIM * IDIM, (long)HDIM * IDIM / 8);
  k_cvt_w13<<<dim3(2048), dim3(256), 0, stream>>>(w13, w13 + (size_t)IDIM * HDIM, w13b, NEXP, (long)2 * IDIM * HDIM);
  k_cvt_w13<<<dim3(512),  dim3(256), 0, stream>>>(sw1, sw3, w13b + (size_t)NEXP * 2 * IDIM * HDIM, 1, 0L);

  k_gate<<<dim3(T_TOK / 32), dim3(256), 0, stream>>>(x, gate_w, idx, wts);
  k_assign<<<dim3(NEXP + 1), dim3(256), 0, stream>>>(idx, etok, pos, cnts);

  // flattened grid: 4 x-tiles * 16 y-tiles * 33 experts = 2112 blocks (8 XCDs * 264)
  k_gemm8<HDIM, true,  true ><<<dim3(2112), dim3(512), 0, stream>>>(xb,   w13b, u_ws,  etok, cnts);
  k_gemm8<IDIM, false, false><<<dim3(2112), dim3(512), 0, stream>>>(u_ws, w2b,  oe_ws, etok, cnts);

  k_combine<<<dim3(T_TOK), dim3(256), 0, stream>>>(oe_ws, idx, wts, pos, y);
}

// Round 3
// 321.044 us; speedup vs baseline: 1.1804x; 1.1804x over previous
//
#include <hip/hip_runtime.h>

typedef unsigned short u16;
typedef unsigned int u32;
typedef float f32x4 __attribute__((ext_vector_type(4)));
typedef __bf16 bf16x8 __attribute__((ext_vector_type(8)));

#define T_TOK 4096
#define HDIM 1024
#define IDIM 512
#define NEXP 32
#define KSEL 8
#define CAPE 2048
#define NROW (NEXP*CAPE + T_TOK)   // 69632 rows total (experts + shared)
#define MAXTILE 528                // 33 experts * 16 y-tiles max
#define MAXWG  (MAXTILE*4)         // 2112

__device__ __forceinline__ u16 f32_to_bf16(float f) {
  u32 x = __float_as_uint(f);
  u32 r = (x + 0x7FFFu + ((x >> 16) & 1u)) >> 16;   // RNE; inputs finite
  return (u16)r;
}
__device__ __forceinline__ float bf16_to_f32(u16 u) {
  return __uint_as_float(((u32)u) << 16);
}

// ---------------- fp32 -> bf16 plain convert (n8 = count of 8-elem chunks) ----------------
__global__ __launch_bounds__(256) void k_cvt(const float* __restrict__ src, u16* __restrict__ dst, long n8) {
  long i = blockIdx.x * 256L + threadIdx.x;
  long stride = (long)gridDim.x * 256L;
  for (long j = i; j < n8; j += stride) {
    float4 a = reinterpret_cast<const float4*>(src)[2*j];
    float4 b = reinterpret_cast<const float4*>(src)[2*j+1];
    ushort4 lo, hi;
    lo.x=f32_to_bf16(a.x); lo.y=f32_to_bf16(a.y); lo.z=f32_to_bf16(a.z); lo.w=f32_to_bf16(a.w);
    hi.x=f32_to_bf16(b.x); hi.y=f32_to_bf16(b.y); hi.z=f32_to_bf16(b.z); hi.w=f32_to_bf16(b.w);
    reinterpret_cast<ushort4*>(dst)[2*j]   = lo;
    reinterpret_cast<ushort4*>(dst)[2*j+1] = hi;
  }
}

// ---------------- w13 convert with 16-row w1/w3 interleave ----------------
__global__ __launch_bounds__(256) void k_cvt_w13(const float* __restrict__ src1, const float* __restrict__ src3,
                                                 u16* __restrict__ dst, int nexp, long sstride) {
  long n8 = (long)nexp * 1024 * 128;
  long i = blockIdx.x * 256L + threadIdx.x;
  long stride = (long)gridDim.x * 256L;
  for (long j = i; j < n8; j += stride) {
    int e   = (int)(j >> 17);
    int rem = (int)(j & 131071);
    int rowd = rem >> 7;
    int c8   = rem & 127;
    int c = rowd >> 4, cw = rowd & 15;
    int srow = (c >> 1) * 16 + cw;
    const float* s = ((c & 1) ? src3 : src1) + (long)e * sstride + (long)srow * HDIM + c8 * 8;
    float4 a = reinterpret_cast<const float4*>(s)[0];
    float4 b = reinterpret_cast<const float4*>(s)[1];
    ushort4 lo, hi;
    lo.x=f32_to_bf16(a.x); lo.y=f32_to_bf16(a.y); lo.z=f32_to_bf16(a.z); lo.w=f32_to_bf16(a.w);
    hi.x=f32_to_bf16(b.x); hi.y=f32_to_bf16(b.y); hi.z=f32_to_bf16(b.z); hi.w=f32_to_bf16(b.w);
    u16* d = dst + ((long)e * 1024 + rowd) * HDIM + c8 * 8;
    reinterpret_cast<ushort4*>(d)[0] = lo;
    reinterpret_cast<ushort4*>(d)[1] = hi;
  }
}

// ---------------- gating: fp64 scores + group-limited top-k ----------------
__global__ __launch_bounds__(256) void k_gate(const float* __restrict__ x, const float* __restrict__ gw,
                                              int* __restrict__ idx, float* __restrict__ wts) {
  __shared__ float xs[32][129];
  __shared__ float gs_[32][129];
  __shared__ double sc[32][32];
  const int tid = threadIdx.x;
  const int t0 = blockIdx.x * 32;
  const int tl = tid & 31, g = tid >> 5;
  double acc0 = 0, acc1 = 0, acc2 = 0, acc3 = 0;
  for (int k0 = 0; k0 < HDIM; k0 += 128) {
#pragma unroll
    for (int q = 0; q < 4; ++q) {
      int f = tid + 256 * q;
      int row = f >> 5, c4 = (f & 31) * 4;
      float4 v = *reinterpret_cast<const float4*>(x + (long)(t0 + row) * HDIM + k0 + c4);
      xs[row][c4+0]=v.x; xs[row][c4+1]=v.y; xs[row][c4+2]=v.z; xs[row][c4+3]=v.w;
      float4 w = *reinterpret_cast<const float4*>(gw + (long)row * HDIM + k0 + c4);
      gs_[row][c4+0]=w.x; gs_[row][c4+1]=w.y; gs_[row][c4+2]=w.z; gs_[row][c4+3]=w.w;
    }
    __syncthreads();
#pragma unroll 4
    for (int kk = 0; kk < 128; ++kk) {
      double xv = (double)xs[tl][kk];
      acc0 += xv * (double)gs_[g     ][kk];
      acc1 += xv * (double)gs_[g +  8][kk];
      acc2 += xv * (double)gs_[g + 16][kk];
      acc3 += xv * (double)gs_[g + 24][kk];
    }
    __syncthreads();
  }
  sc[tl][g     ] = 1.0 / (1.0 + exp(-acc0));
  sc[tl][g +  8] = 1.0 / (1.0 + exp(-acc1));
  sc[tl][g + 16] = 1.0 / (1.0 + exp(-acc2));
  sc[tl][g + 24] = 1.0 / (1.0 + exp(-acc3));
  __syncthreads();
  if (tid < 32) {
    int t = t0 + tid;
    double gsc[8];
#pragma unroll
    for (int gg = 0; gg < 8; ++gg) {
      double mx = sc[tid][4*gg];
#pragma unroll
      for (int j = 1; j < 4; ++j) mx = fmax(mx, sc[tid][4*gg + j]);
      gsc[gg] = mx;
    }
    unsigned gmask = 0;
    for (int it = 0; it < 4; ++it) {
      double best = -1e300; int bi = 0;
      for (int gg = 0; gg < 8; ++gg)
        if (!((gmask >> gg) & 1) && gsc[gg] > best) { best = gsc[gg]; bi = gg; }
      gmask |= 1u << bi;
    }
    unsigned emask = 0; int ei[KSEL]; double ew[KSEL]; double wsum = 0;
    for (int it = 0; it < KSEL; ++it) {
      double best = -1e300; int bi = 0;
      for (int e = 0; e < NEXP; ++e)
        if (((gmask >> (e >> 2)) & 1) && !((emask >> e) & 1)) {
          double v = sc[tid][e];
          if (v > best) { best = v; bi = e; }
        }
      emask |= 1u << bi; ei[it] = bi; ew[it] = best; wsum += best;
    }
    double s = 2.5 / (wsum + 1e-20);
    for (int k = 0; k < KSEL; ++k) { idx[t*KSEL + k] = ei[k]; wts[t*KSEL + k] = (float)(ew[k] * s); }
  }
}

// ---------------- capacity assignment: ballot-scan, 1024 threads / expert ----------------
__global__ __launch_bounds__(1024) void k_assign(const int* __restrict__ idx,
                                                 int* __restrict__ etok, int* __restrict__ pos,
                                                 int* __restrict__ cnts) {
  const int e = blockIdx.x;
  const int tid = threadIdx.x;
  if (e == NEXP) {
    for (int t = tid; t < T_TOK; t += 1024) etok[NEXP*CAPE + t] = t;
    if (tid == 0) cnts[NEXP] = T_TOK;
    return;
  }
  __shared__ int wbase[17];          // [0..15] exclusive wave offsets, [16] chunk total
  const int wid = tid >> 6, lane = tid & 63;
  int base = 0;
  for (int c = 0; c < T_TOK / 1024; ++c) {
    int t = c * 1024 + tid;
    int found = -1;
#pragma unroll
    for (int k = 0; k < KSEL; ++k) if (idx[t*KSEL + k] == e) found = k;
    unsigned long long mask = __ballot(found >= 0);
    int myrank = __popcll(mask & ((1ull << lane) - 1ull));
    __syncthreads();
    if (lane == 0) wbase[wid] = __popcll(mask);
    __syncthreads();
    if (tid == 0) {
      int run = 0;
#pragma unroll
      for (int w = 0; w < 16; ++w) { int v = wbase[w]; wbase[w] = run; run += v; }
      wbase[16] = run;
    }
    __syncthreads();
    if (found >= 0) {
      int slot = base + wbase[wid] + myrank;
      pos[t*KSEL + found] = slot;
      if (slot < CAPE) etok[e*CAPE + slot] = t;
    }
    base += wbase[16];
    __syncthreads();
  }
  if (tid == 0) cnts[e] = min(base, CAPE);
}

// ---------------- tile scheduler: compact (e,yt) work list + total wg count ----------------
__global__ __launch_bounds__(64) void k_sched(const int* __restrict__ cnts,
                                              int* __restrict__ list, int* __restrict__ tot) {
  int lane = threadIdx.x;
  int nt = (lane < NEXP + 1) ? ((cnts[lane] + 255) >> 8) : 0;
  int incl = nt;
#pragma unroll
  for (int o = 1; o < 64; o <<= 1) { int v = __shfl_up(incl, o); if (lane >= o) incl += v; }
  int off = incl - nt;
  if (lane == NEXP) tot[0] = 4 * incl;    // inclusive at lane 32 = total tiles
  for (int i = 0; i < nt; ++i) list[off + i] = lane * 16 + i;
}

// ---------------- grouped GEMM: 256x256 tile, BK=64, 8-phase counted-vmcnt schedule ----------------
// T1 bijective XCD swizzle over the ACTIVE prefix (m204) + T2 XOR LDS swizzle +
// T3/T4 8-phase counted vmcnt + T5 setprio. Work items come from the compact list.

#define GLDS(gp, lp) __builtin_amdgcn_global_load_lds( \
    (const __attribute__((address_space(1))) void*)(gp), \
    (__attribute__((address_space(3))) void*)(lp), 16, 0, 0)

template<int KDIM, bool GATHER, bool ACT>
__global__ __launch_bounds__(512, 2) void k_gemm8(const u16* __restrict__ A, const u16* __restrict__ Ball,
                                                  u16* __restrict__ out,
                                                  const int* __restrict__ etok, const int* __restrict__ cnts,
                                                  const int* __restrict__ list, const int* __restrict__ tot) {
  constexpr int NT = KDIM / 64;
  constexpr int MSK = NT - 1;
  __shared__ u16 lds[65536];            // [dbuf 2][op 2][256*64], 128 KiB

  const int n = tot[0];                 // active wg count (4 * tiles)
  const int bid0 = blockIdx.x;
  if (bid0 >= n) return;
  // m204 bijective XCD swizzle over [0,n): XCD k gets a contiguous chunk of work
  const int q = n >> 3, r = n & 7, xc = bid0 & 7, o = bid0 >> 3;
  const int wg = (xc < r ? xc * (q + 1) : r * (q + 1) + (xc - r) * q) + o;
  const int item = list[wg >> 2];
  const int e = item >> 4, yt = item & 15, xt = wg & 3;

  const int cnt = cnts[e];
  const int brow = yt * 256;
  const int rv = min(256, cnt - brow);
  const long rowbase = (long)e * CAPE;
  const u16* Bexp = Ball + (size_t)e * (size_t)(1024 * KDIM);

  const int tid = threadIdx.x;
  const int wave = tid >> 6, lane = tid & 63;
  const int wm = wave >> 2, wn = wave & 3;
  const int lr = lane & 15;
  const int lk = (lane >> 4) * 16;      // byte offset of this lane's K-slot

  // staging source pointers: sub-issue j covers tile rows j*64..j*64+63
  const u16* pa[4]; const u16* pb[4];
#pragma unroll
  for (int j = 0; j < 4; ++j) {
    int row = j*64 + (tid >> 3);
    int sl = (tid & 7) ^ (row & 7);                  // pre-swizzled source chunk
    long arow;
    if (GATHER) arow = (row < rv) ? (long)etok[rowbase + brow + row] : 0L;
    else        arow = rowbase + brow + row;
    pa[j] = A + arow * KDIM + sl * 8;
    pb[j] = Bexp + ((long)(xt*256 + row)) * KDIM + sl * 8;
  }

  // stage half h (0: rows 0-127, 1: rows 128-255) of operand o of K-tile st
  auto STAGE = [&](int st, int op, int h) {
    int dbase = (st & 1) * 32768 + op * 16384;
    const u16* const* pp = op ? pb : pa;
#pragma unroll
    for (int s = 0; s < 2; ++s) {
      int j = h*2 + s;
      GLDS(pp[j] + st * 64, &lds[dbase + j*4096 + wave*512]);
    }
  };

  const char* ldsb = (const char*)lds;
  auto RD = [&](int d, int op, int rr, int kk) -> bf16x8 {
    int bc = (kk*64 + lk) ^ ((rr & 7) << 4);
    return *(const bf16x8*)(ldsb + (size_t)(d*65536 + op*32768 + rr*128 + bc));
  };

  f32x4 acc[8][4];
#pragma unroll
  for (int m = 0; m < 8; ++m)
#pragma unroll
    for (int nn = 0; nn < 4; ++nn) acc[m][nn] = (f32x4){0.f,0.f,0.f,0.f};

  // prologue: tile0 fully, tile1 {A0,B0,B1}; A1(1) staged at t=0.q0
  STAGE(0,0,0); STAGE(0,1,0); STAGE(0,0,1); STAGE(0,1,1);
  STAGE(1,0,0); STAGE(1,1,0); STAGE(1,1,1);
  asm volatile("s_waitcnt vmcnt(6)" ::: "memory");    // tile0's 8 loads landed
  __builtin_amdgcn_sched_barrier(0);
  __builtin_amdgcn_s_barrier();

  bf16x8 a[4][2], b[2][2], b0h[2][2];

  for (int t = 0; t < NT; ++t) {
    const int d = t & 1;
    // ---------- q0: (mq=0, nq=0) — read A0(8) + B0(4); stage A1(t+1) ----------
#pragma unroll
    for (int m = 0; m < 4; ++m)
#pragma unroll
      for (int kk = 0; kk < 2; ++kk) a[m][kk] = RD(d, 0, wm*64 + m*16 + lr, kk);
#pragma unroll
    for (int nn = 0; nn < 2; ++nn)
#pragma unroll
      for (int kk = 0; kk < 2; ++kk) { b[nn][kk] = RD(d, 1, wn*32 + nn*16 + lr, kk); b0h[nn][kk] = b[nn][kk]; }
    STAGE((t+1) & MSK, 0, 1);
    __builtin_amdgcn_s_barrier();
    asm volatile("s_waitcnt lgkmcnt(0)" ::: "memory");
    __builtin_amdgcn_sched_barrier(0);
    __builtin_amdgcn_s_setprio(1);
#pragma unroll
    for (int m = 0; m < 4; ++m)
#pragma unroll
      for (int nn = 0; nn < 2; ++nn)
#pragma unroll
        for (int kk = 0; kk < 2; ++kk)
          acc[m][nn] = __builtin_amdgcn_mfma_f32_16x16x32_bf16(a[m][kk], b[nn][kk], acc[m][nn], 0, 0, 0);
    __builtin_amdgcn_s_setprio(0);
    __builtin_amdgcn_sched_barrier(0);
    __builtin_amdgcn_s_barrier();
    // ---------- q1: (mq=0, nq=1) — read B1(4); stage B0(t+2) ----------
#pragma unroll
    for (int nn = 0; nn < 2; ++nn)
#pragma unroll
      for (int kk = 0; kk < 2; ++kk) b[nn][kk] = RD(d, 1, 128 + wn*32 + nn*16 + lr, kk);
    STAGE((t+2) & MSK, 1, 0);
    __builtin_amdgcn_s_barrier();
    asm volatile("s_waitcnt lgkmcnt(0)" ::: "memory");
    __builtin_amdgcn_sched_barrier(0);
    __builtin_amdgcn_s_setprio(1);
#pragma unroll
    for (int m = 0; m < 4; ++m)
#pragma unroll
      for (int nn = 0; nn < 2; ++nn)
#pragma unroll
        for (int kk = 0; kk < 2; ++kk)
          acc[m][2+nn] = __builtin_amdgcn_mfma_f32_16x16x32_bf16(a[m][kk], b[nn][kk], acc[m][2+nn], 0, 0, 0);
    __builtin_amdgcn_s_setprio(0);
    __builtin_amdgcn_sched_barrier(0);
    __builtin_amdgcn_s_barrier();
    // ---------- q2: (mq=1, nq=1) — read A1(8); stage A0(t+2) ----------
#pragma unroll
    for (int m = 0; m < 4; ++m)
#pragma unroll
      for (int kk = 0; kk < 2; ++kk) a[m][kk] = RD(d, 0, 128 + wm*64 + m*16 + lr, kk);
    STAGE((t+2) & MSK, 0, 0);
    __builtin_amdgcn_s_barrier();
    asm volatile("s_waitcnt lgkmcnt(0)" ::: "memory");
    __builtin_amdgcn_sched_barrier(0);
    __builtin_amdgcn_s_setprio(1);
#pragma unroll
    for (int m = 0; m < 4; ++m)
#pragma unroll
      for (int nn = 0; nn < 2; ++nn)
#pragma unroll
        for (int kk = 0; kk < 2; ++kk)
          acc[4+m][2+nn] = __builtin_amdgcn_mfma_f32_16x16x32_bf16(a[m][kk], b[nn][kk], acc[4+m][2+nn], 0, 0, 0);
    __builtin_amdgcn_s_setprio(0);
    __builtin_amdgcn_sched_barrier(0);
    __builtin_amdgcn_s_barrier();
    // ---------- q3: (mq=1, nq=0) — no ds_reads (A1 + held B0); stage B1(t+2) ----------
    STAGE((t+2) & MSK, 1, 1);
    __builtin_amdgcn_s_barrier();
    asm volatile("s_waitcnt lgkmcnt(0)" ::: "memory");
    __builtin_amdgcn_sched_barrier(0);
    __builtin_amdgcn_s_setprio(1);
#pragma unroll
    for (int m = 0; m < 4; ++m)
#pragma unroll
      for (int nn = 0; nn < 2; ++nn)
#pragma unroll
        for (int kk = 0; kk < 2; ++kk)
          acc[4+m][nn] = __builtin_amdgcn_mfma_f32_16x16x32_bf16(a[m][kk], b0h[nn][kk], acc[4+m][nn], 0, 0, 0);
    __builtin_amdgcn_s_setprio(0);
    __builtin_amdgcn_sched_barrier(0);
    asm volatile("s_waitcnt vmcnt(6)" ::: "memory");    // K-tile boundary: tile t+1 fully landed
    __builtin_amdgcn_s_barrier();
  }

  // epilogue: C/D map col=lane&15, row=(lane>>4)*4+reg  [verified m89]
  const int rl = (lane >> 4) << 2;
  if (ACT) {
#pragma unroll
    for (int mq = 0; mq < 2; ++mq)
#pragma unroll
      for (int m = 0; m < 4; ++m) {
        int rbase = mq*128 + wm*64 + m*16 + rl;
#pragma unroll
        for (int nq = 0; nq < 2; ++nq) {
          f32x4 h1 = acc[mq*4+m][nq*2], h3 = acc[mq*4+m][nq*2+1];
          int ucol = xt*128 + nq*64 + wn*16 + lr;
#pragma unroll
          for (int j = 0; j < 4; ++j) {
            int lrow = rbase + j;
            if (lrow < rv) {
              float v1 = h1[j];
              float uu = v1 / (1.f + __expf(-v1)) * h3[j];   // silu(h1)*h3
              out[(size_t)(rowbase + brow + lrow) * IDIM + ucol] = f32_to_bf16(uu);
            }
          }
        }
      }
  } else {
#pragma unroll
    for (int mq = 0; mq < 2; ++mq)
#pragma unroll
      for (int m = 0; m < 4; ++m) {
        int rbase = mq*128 + wm*64 + m*16 + rl;
#pragma unroll
        for (int nq = 0; nq < 2; ++nq)
#pragma unroll
          for (int nn = 0; nn < 2; ++nn) {
            int col = xt*256 + nq*128 + wn*32 + nn*16 + lr;
            f32x4 v = acc[mq*4+m][nq*2+nn];
#pragma unroll
            for (int j = 0; j < 4; ++j) {
              int lrow = rbase + j;
              if (lrow < rv)
                out[(size_t)(rowbase + brow + lrow) * HDIM + col] = f32_to_bf16(v[j]);
            }
          }
      }
  }
}

// ---------------- combine: y[t] = sum_k w_k * oe[e_k][pos_k] + shared[t] ----------------
__global__ __launch_bounds__(256) void k_combine(const u16* __restrict__ oe,
                                                 const int* __restrict__ idx, const float* __restrict__ wts,
                                                 const int* __restrict__ pos, float* __restrict__ y) {
  int t = blockIdx.x;
  int h0 = threadIdx.x * 4;
  float a0 = 0, a1 = 0, a2 = 0, a3 = 0;
#pragma unroll
  for (int k = 0; k < KSEL; ++k) {
    int e = idx[t*KSEL + k];
    int p = pos[t*KSEL + k];
    if (p < CAPE) {
      float w = wts[t*KSEL + k];
      ushort4 v = *reinterpret_cast<const ushort4*>(oe + ((long)e * CAPE + p) * HDIM + h0);
      a0 += w * bf16_to_f32(v.x); a1 += w * bf16_to_f32(v.y);
      a2 += w * bf16_to_f32(v.z); a3 += w * bf16_to_f32(v.w);
    }
  }
  ushort4 s = *reinterpret_cast<const ushort4*>(oe + ((long)NEXP * CAPE + t) * HDIM + h0);
  a0 += bf16_to_f32(s.x); a1 += bf16_to_f32(s.y); a2 += bf16_to_f32(s.z); a3 += bf16_to_f32(s.w);
  float4 o; o.x = a0; o.y = a1; o.z = a2; o.w = a3;
  reinterpret_cast<float4*>(y + (long)t * HDIM)[threadIdx.x] = o;
}

extern "C" void kernel_launch(void* const* d_in, const int* in_sizes, int n_in,
                              void* d_out, int out_size, void* d_ws, size_t ws_size,
                              hipStream_t stream) {
  const float* x      = (const float*)d_in[0];
  const float* gate_w = (const float*)d_in[1];
  const float* w13    = (const float*)d_in[2];
  const float* w2     = (const float*)d_in[3];
  const float* sw1    = (const float*)d_in[4];
  const float* sw2    = (const float*)d_in[5];
  const float* sw3    = (const float*)d_in[6];
  float* y = (float*)d_out;

  char* base = (char*)d_ws;
  size_t off = 0;
  auto alloc = [&](size_t bytes) -> void* {
    void* p = base + off;
    off = (off + bytes + 255) & ~(size_t)255;
    return p;
  };
  u16* xb    = (u16*)alloc((size_t)T_TOK * HDIM * 2);
  u16* w13b  = (u16*)alloc((size_t)(NEXP + 1) * 2 * IDIM * HDIM * 2);
  u16* w2b   = (u16*)alloc((size_t)(NEXP + 1) * HDIM * IDIM * 2);
  u16* u_ws  = (u16*)alloc((size_t)NROW * IDIM * 2);
  u16* oe_ws = (u16*)alloc((size_t)NROW * HDIM * 2);
  int*   idx  = (int*)alloc((size_t)T_TOK * KSEL * 4);
  float* wts  = (float*)alloc((size_t)T_TOK * KSEL * 4);
  int*   pos  = (int*)alloc((size_t)T_TOK * KSEL * 4);
  int*   etok = (int*)alloc((size_t)NROW * 4);
  int*   cnts = (int*)alloc(256);
  int*   list = (int*)alloc(MAXTILE * 4);
  int*   tot  = (int*)alloc(64);
  if (off > ws_size) return;

  k_cvt<<<dim3(2048), dim3(256), 0, stream>>>(x, xb, (long)T_TOK * HDIM / 8);
  k_cvt<<<dim3(2048), dim3(256), 0, stream>>>(w2, w2b, (long)NEXP * HDIM * IDIM / 8);
  k_cvt<<<dim3(256),  dim3(256), 0, stream>>>(sw2, w2b + (size_t)NEXP * HDIM * IDIM, (long)HDIM * IDIM / 8);
  k_cvt_w13<<<dim3(2048), dim3(256), 0, stream>>>(w13, w13 + (size_t)IDIM * HDIM, w13b, NEXP, (long)2 * IDIM * HDIM);
  k_cvt_w13<<<dim3(512),  dim3(256), 0, stream>>>(sw1, sw3, w13b + (size_t)NEXP * 2 * IDIM * HDIM, 1, 0L);

  k_gate<<<dim3(T_TOK / 32), dim3(256), 0, stream>>>(x, gate_w, idx, wts);
  k_assign<<<dim3(NEXP + 1), dim3(1024), 0, stream>>>(idx, etok, pos, cnts);
  k_sched<<<dim3(1), dim3(64), 0, stream>>>(cnts, list, tot);

  // worst-case grid; blocks beyond the active prefix exit via tot[0]
  k_gemm8<HDIM, true,  true ><<<dim3(MAXWG), dim3(512), 0, stream>>>(xb,   w13b, u_ws,  etok, cnts, list, tot);
  k_gemm8<IDIM, false, false><<<dim3(MAXWG), dim3(512), 0, stream>>>(u_ws, w2b,  oe_ws, etok, cnts, list, tot);

  k_combine<<<dim3(T_TOK), dim3(256), 0, stream>>>(oe_ws, idx, wts, pos, y);
}

// Round 4
// 319.024 us; speedup vs baseline: 1.1879x; 1.0063x over previous
//
#include <hip/hip_runtime.h>

typedef unsigned short u16;
typedef unsigned int u32;
typedef float f32x4 __attribute__((ext_vector_type(4)));
typedef __bf16 bf16x8 __attribute__((ext_vector_type(8)));
typedef u32 u32x4 __attribute__((ext_vector_type(4)));

#define T_TOK 4096
#define HDIM 1024
#define IDIM 512
#define NEXP 32
#define KSEL 8
#define CAPE 2048
#define NROW (NEXP*CAPE + T_TOK)   // 69632 rows total (experts + shared)
#define MAXTILE 528                // 33 experts * 16 y-tiles max
#define MAXWG  (MAXTILE*4)         // 2112

__device__ __forceinline__ u16 f32_to_bf16(float f) {
  u32 x = __float_as_uint(f);
  u32 r = (x + 0x7FFFu + ((x >> 16) & 1u)) >> 16;   // RNE; inputs finite
  return (u16)r;
}
__device__ __forceinline__ float bf16_to_f32(u16 u) {
  return __uint_as_float(((u32)u) << 16);
}

// ---------------- gating: fp64 logits + group-limited top-k; fused x->bf16 ----------------
__global__ __launch_bounds__(256) void k_gate(const float* __restrict__ x, const float* __restrict__ gw,
                                              int* __restrict__ idx, float* __restrict__ wts,
                                              u16* __restrict__ xb, int* __restrict__ done) {
  __shared__ float xs[32][129];
  __shared__ float gs_[32][129];
  __shared__ double sc[32][32];
  const int tid = threadIdx.x;
  const int t0 = blockIdx.x * 32;
  const int tl = tid & 31, g = tid >> 5;
  if (blockIdx.x == 0 && tid == 0) done[0] = 0;   // reset sched rendezvous (gate completes before assign)
  double acc0 = 0, acc1 = 0, acc2 = 0, acc3 = 0;
  for (int k0 = 0; k0 < HDIM; k0 += 128) {
#pragma unroll
    for (int q = 0; q < 4; ++q) {
      int f = tid + 256 * q;
      int row = f >> 5, c4 = (f & 31) * 4;
      float4 v = *reinterpret_cast<const float4*>(x + (long)(t0 + row) * HDIM + k0 + c4);
      xs[row][c4+0]=v.x; xs[row][c4+1]=v.y; xs[row][c4+2]=v.z; xs[row][c4+3]=v.w;
      ushort4 xv; xv.x=f32_to_bf16(v.x); xv.y=f32_to_bf16(v.y); xv.z=f32_to_bf16(v.z); xv.w=f32_to_bf16(v.w);
      *reinterpret_cast<ushort4*>(xb + (long)(t0 + row) * HDIM + k0 + c4) = xv;   // fused x convert
      float4 w = *reinterpret_cast<const float4*>(gw + (long)row * HDIM + k0 + c4);
      gs_[row][c4+0]=w.x; gs_[row][c4+1]=w.y; gs_[row][c4+2]=w.z; gs_[row][c4+3]=w.w;
    }
    __syncthreads();
#pragma unroll 4
    for (int kk = 0; kk < 128; ++kk) {
      double xv = (double)xs[tl][kk];
      acc0 += xv * (double)gs_[g     ][kk];
      acc1 += xv * (double)gs_[g +  8][kk];
      acc2 += xv * (double)gs_[g + 16][kk];
      acc3 += xv * (double)gs_[g + 24][kk];
    }
    __syncthreads();
  }
  sc[tl][g     ] = acc0;   // raw logits; sigmoid is monotonic -> same top-k order
  sc[tl][g +  8] = acc1;
  sc[tl][g + 16] = acc2;
  sc[tl][g + 24] = acc3;
  __syncthreads();
  if (tid < 32) {
    int t = t0 + tid;
    double gsc[8];
#pragma unroll
    for (int gg = 0; gg < 8; ++gg) {
      double mx = sc[tid][4*gg];
#pragma unroll
      for (int j = 1; j < 4; ++j) mx = fmax(mx, sc[tid][4*gg + j]);
      gsc[gg] = mx;
    }
    unsigned gmask = 0;
    for (int it = 0; it < 4; ++it) {          // top-4 groups, strict >, first index wins
      double best = -1e300; int bi = 0;
      for (int gg = 0; gg < 8; ++gg)
        if (!((gmask >> gg) & 1) && gsc[gg] > best) { best = gsc[gg]; bi = gg; }
      gmask |= 1u << bi;
    }
    unsigned emask = 0; int ei[KSEL]; double ew[KSEL]; double wsum = 0;
    for (int it = 0; it < KSEL; ++it) {       // top-8 experts on logits
      double best = -1e300; int bi = 0;
      for (int e = 0; e < NEXP; ++e)
        if (((gmask >> (e >> 2)) & 1) && !((emask >> e) & 1)) {
          double v = sc[tid][e];
          if (v > best) { best = v; bi = e; }
        }
      emask |= 1u << bi; ei[it] = bi;
      double sg = 1.0 / (1.0 + exp(-best));   // sigmoid only for the 8 selected
      ew[it] = sg; wsum += sg;
    }
    double s = 2.5 / (wsum + 1e-20);
    for (int k = 0; k < KSEL; ++k) { idx[t*KSEL + k] = ei[k]; wts[t*KSEL + k] = (float)(ew[k] * s); }
  }
}

// ---------------- capacity assignment (ballot-scan) + inline tile scheduler ----------------
__global__ __launch_bounds__(1024) void k_assign(const int* __restrict__ idx,
                                                 int* __restrict__ etok, int* __restrict__ pos,
                                                 int* __restrict__ cnts,
                                                 int* __restrict__ list, int* __restrict__ tot,
                                                 int* __restrict__ done) {
  const int e = blockIdx.x;
  const int tid = threadIdx.x;
  int base = 0;
  if (e == NEXP) {                             // shared "expert": identity token list
    for (int t = tid; t < T_TOK; t += 1024) etok[NEXP*CAPE + t] = t;
    base = T_TOK;
  } else {
    __shared__ int wbase[17];
    const int wid = tid >> 6, lane = tid & 63;
    for (int c = 0; c < T_TOK / 1024; ++c) {
      int t = c * 1024 + tid;
      int found = -1;
#pragma unroll
      for (int k = 0; k < KSEL; ++k) if (idx[t*KSEL + k] == e) found = k;
      unsigned long long mask = __ballot(found >= 0);
      int myrank = __popcll(mask & ((1ull << lane) - 1ull));
      __syncthreads();
      if (lane == 0) wbase[wid] = __popcll(mask);
      __syncthreads();
      if (tid == 0) {
        int run = 0;
#pragma unroll
        for (int w = 0; w < 16; ++w) { int v = wbase[w]; wbase[w] = run; run += v; }
        wbase[16] = run;
      }
      __syncthreads();
      if (found >= 0) {
        int slot = base + wbase[wid] + myrank;
        pos[t*KSEL + found] = slot;
        if (slot < CAPE) etok[e*CAPE + slot] = t;
      }
      base += wbase[16];
      __syncthreads();
    }
    base = min(base, CAPE);
  }
  if (tid == 0) {
    cnts[e] = base;
    __threadfence();
    if (atomicAdd(done, 1) == NEXP) {          // last finisher builds the compact work list
      __threadfence();
      int run = 0;
      for (int ee = 0; ee <= NEXP; ++ee) {
        int c = atomicAdd(&cnts[ee], 0);       // device-scope read
        int nt = (c + 255) >> 8;
        for (int i = 0; i < nt; ++i) list[run + i] = ee * 16 + i;
        run += nt;
      }
      tot[0] = run * 4;
    }
  }
}

// ---------------- grouped GEMM: 256x256, BK=64, 8-phase counted vmcnt; B staged from fp32 ----------------
// A: bf16 via global_load_lds (linear dest, pre-swizzled source).  B: fp32 -> regs (issued one
// K-tile ahead) -> v_cvt_pk_bf16_f32 -> swizzled ds_write_b128 (write unit c16^(row&7) == read's XOR).
// vmcnt FIFO per tile (12 ops): q0 +2 A1(t+1) | q1 +4 B0(t+2) | q2 +2 A0(t+2) | q3 +4 B1(t+2).
// Waits: q1 vmcnt(8) drains B0(t+1) regs; q3 vmcnt(8) drains B1(t+1) regs (+A0(t+1));
// boundary vmcnt(10) drains A1(t+1). Prologue replays this issue order so counts are uniform.

#define GLDS(gp, lp) __builtin_amdgcn_global_load_lds( \
    (const __attribute__((address_space(1))) void*)(gp), \
    (__attribute__((address_space(3))) void*)(lp), 16, 0, 0)

template<int KDIM, bool GATHER, bool ACT, bool W13MAP>
__global__ __launch_bounds__(512, 2) void k_gemm8(const u16* __restrict__ A,
                                                  const float* __restrict__ Bf,
                                                  const float* __restrict__ Bs1,
                                                  const float* __restrict__ Bs3,
                                                  u16* __restrict__ out,
                                                  const int* __restrict__ etok, const int* __restrict__ cnts,
                                                  const int* __restrict__ list, const int* __restrict__ tot) {
  constexpr int NT = KDIM / 64;
  __shared__ u16 lds[65536];            // [dbuf 2][A 32KB | B 32KB], 128 KiB

  const int n = tot[0];
  const int bid0 = blockIdx.x;
  if (bid0 >= n) return;
  const int q = n >> 3, r = n & 7, xc = bid0 & 7, o = bid0 >> 3;
  const int wg = (xc < r ? xc * (q + 1) : r * (q + 1) + (xc - r) * q) + o;
  const int item = list[wg >> 2];
  const int e = item >> 4, yt = item & 15, xt = wg & 3;

  const int cnt = cnts[e];
  const int brow = yt * 256;
  const int rv = min(256, cnt - brow);
  const long rowbase = (long)e * CAPE;

  const int tid = threadIdx.x;
  const int wave = tid >> 6, lane = tid & 63;
  const int wm = wave >> 2, wn = wave & 3;
  const int lr = lane & 15;
  const int lk = (lane >> 4) * 16;

  // A staging source pointers (sub-issue j covers tile rows j*64..j*64+63)
  const u16* pa[4];
#pragma unroll
  for (int j = 0; j < 4; ++j) {
    int row = j*64 + (tid >> 3);
    int sl = (tid & 7) ^ (row & 7);
    long arow;
    if (GATHER) arow = (row < rv) ? (long)etok[rowbase + brow + row] : 0L;
    else        arow = rowbase + brow + row;
    pa[j] = A + arow * KDIM + sl * 8;
  }

  // B fp32 per-thread row pointers (half h: rows h*128 + tid>>2; cols (tid&3)*16)
  const float* pbF[2];
#pragma unroll
  for (int h = 0; h < 2; ++h) {
    int rbw = xt*256 + h*128 + (tid >> 2);
    const float* bs;
    if constexpr (W13MAP) {                     // w1/w3 16-row interleave (same map as old k_cvt_w13)
      int sel = (rbw >> 4) & 1;
      int srow = ((rbw >> 5) << 4) | (rbw & 15);
      if (e < NEXP) bs = Bf + ((size_t)e * 1024 + sel * 512 + srow) * (size_t)KDIM;
      else          bs = (sel ? Bs3 : Bs1) + (size_t)srow * KDIM;
    } else {
      if (e < NEXP) bs = Bf + ((size_t)e * 1024 + rbw) * (size_t)KDIM;
      else          bs = Bs1 + (size_t)rbw * KDIM;
    }
    pbF[h] = bs + (tid & 3) * 16;
  }

  auto STAGEA = [&](int st, int h) {            // A half h of K-tile st -> LDS slot st&1
    int dbase = (st & 1) * 32768;
#pragma unroll
    for (int s = 0; s < 2; ++s) {
      int j = h*2 + s;
      GLDS(pa[j] + st * 64, &lds[dbase + j*4096 + wave*512]);
    }
  };
  auto LOADB = [&](float4* rr, int st, int h) { // issue 4 dwordx4 (clamped: dead slots re-read NT-1)
    const float* p = pbF[h] + (size_t)min(st, NT - 1) * 64;
#pragma unroll
    for (int i = 0; i < 4; ++i) rr[i] = reinterpret_cast<const float4*>(p)[i];
  };
  auto CVTW = [&](const float4* rr, int slot, int h) {  // 16 f32 -> bf16 -> 2 swizzled ds_write_b128
    int rbt = h*128 + (tid >> 2);
    u32 w[8];
#pragma unroll
    for (int i = 0; i < 8; ++i) {
      float f0 = reinterpret_cast<const float*>(rr)[2*i];
      float f1 = reinterpret_cast<const float*>(rr)[2*i + 1];
      asm("v_cvt_pk_bf16_f32 %0, %1, %2" : "=v"(w[i]) : "v"(f0), "v"(f1));
    }
    char* bp = (char*)lds + slot*65536 + 32768 + rbt*128;
    int c0 = ((tid & 3) * 2)     ^ (rbt & 7);
    int c1 = ((tid & 3) * 2 + 1) ^ (rbt & 7);
    *reinterpret_cast<u32x4*>(bp + c0*16) = (u32x4){w[0], w[1], w[2], w[3]};
    *reinterpret_cast<u32x4*>(bp + c1*16) = (u32x4){w[4], w[5], w[6], w[7]};
  };

  const char* ldsb = (const char*)lds;
  auto RD = [&](int d, int op, int rr, int kk) -> bf16x8 {
    int bc = (kk*64 + lk) ^ ((rr & 7) << 4);
    return *(const bf16x8*)(ldsb + (size_t)(d*65536 + op*32768 + rr*128 + bc));
  };

  f32x4 acc[8][4];
#pragma unroll
  for (int m = 0; m < 8; ++m)
#pragma unroll
    for (int nn = 0; nn < 4; ++nn) acc[m][nn] = (f32x4){0.f,0.f,0.f,0.f};

  float4 rB0[4], rB1[4];

  // ---- prologue: replay steady-state issue order for pseudo-tiles t=-2,-1 ----
  asm volatile("s_waitcnt vmcnt(0)" ::: "memory");   // clean slate (setup loads drained)
  LOADB(rB0, 0, 0);          // +4  B0(0)
  STAGEA(0, 0);              // +2  A0(0)
  LOADB(rB1, 0, 1);          // +4  B1(0)
  STAGEA(0, 1);              // +2  A1(0)
  asm volatile("s_waitcnt vmcnt(8)" ::: "memory");   // B0(0) regs ready
  CVTW(rB0, 0, 0);
  LOADB(rB0, 1, 0);          // +4  B0(1)
  STAGEA(1, 0);              // +2  A0(1)
  asm volatile("s_waitcnt vmcnt(8)" ::: "memory");   // B1(0) regs ready
  CVTW(rB1, 0, 1);
  LOADB(rB1, 1, 1);          // +4  B1(1)
  asm volatile("s_waitcnt vmcnt(10)" ::: "memory");  // A0(0), A1(0) landed
  asm volatile("s_waitcnt lgkmcnt(0)" ::: "memory"); // ds_writes done
  __builtin_amdgcn_sched_barrier(0);
  __builtin_amdgcn_s_barrier();

  bf16x8 a[4][2], b[2][2], b0h[2][2];

  for (int t = 0; t < NT; ++t) {
    const int d = t & 1;
    // ---------- q0: read A0(8)+B0(4); stage A1(t+1) ----------
#pragma unroll
    for (int m = 0; m < 4; ++m)
#pragma unroll
      for (int kk = 0; kk < 2; ++kk) a[m][kk] = RD(d, 0, wm*64 + m*16 + lr, kk);
#pragma unroll
    for (int nn = 0; nn < 2; ++nn)
#pragma unroll
      for (int kk = 0; kk < 2; ++kk) { b[nn][kk] = RD(d, 1, wn*32 + nn*16 + lr, kk); b0h[nn][kk] = b[nn][kk]; }
    STAGEA(t + 1, 1);
    __builtin_amdgcn_s_barrier();
    asm volatile("s_waitcnt lgkmcnt(0)" ::: "memory");
    __builtin_amdgcn_sched_barrier(0);
    __builtin_amdgcn_s_setprio(1);
#pragma unroll
    for (int m = 0; m < 4; ++m)
#pragma unroll
      for (int nn = 0; nn < 2; ++nn)
#pragma unroll
        for (int kk = 0; kk < 2; ++kk)
          acc[m][nn] = __builtin_amdgcn_mfma_f32_16x16x32_bf16(a[m][kk], b[nn][kk], acc[m][nn], 0, 0, 0);
    __builtin_amdgcn_s_setprio(0);
    __builtin_amdgcn_sched_barrier(0);
    __builtin_amdgcn_s_barrier();
    // ---------- q1: read B1(4); cvt+write B0(t+1); issue B0(t+2) ----------
#pragma unroll
    for (int nn = 0; nn < 2; ++nn)
#pragma unroll
      for (int kk = 0; kk < 2; ++kk) b[nn][kk] = RD(d, 1, 128 + wn*32 + nn*16 + lr, kk);
    asm volatile("s_waitcnt vmcnt(8)" ::: "memory");   // B0(t+1) regs ready
    CVTW(rB0, d ^ 1, 0);
    LOADB(rB0, t + 2, 0);
    __builtin_amdgcn_s_barrier();
    asm volatile("s_waitcnt lgkmcnt(0)" ::: "memory");
    __builtin_amdgcn_sched_barrier(0);
    __builtin_amdgcn_s_setprio(1);
#pragma unroll
    for (int m = 0; m < 4; ++m)
#pragma unroll
      for (int nn = 0; nn < 2; ++nn)
#pragma unroll
        for (int kk = 0; kk < 2; ++kk)
          acc[m][2+nn] = __builtin_amdgcn_mfma_f32_16x16x32_bf16(a[m][kk], b[nn][kk], acc[m][2+nn], 0, 0, 0);
    __builtin_amdgcn_s_setprio(0);
    __builtin_amdgcn_sched_barrier(0);
    __builtin_amdgcn_s_barrier();
    // ---------- q2: read A1(8); stage A0(t+2) ----------
#pragma unroll
    for (int m = 0; m < 4; ++m)
#pragma unroll
      for (int kk = 0; kk < 2; ++kk) a[m][kk] = RD(d, 0, 128 + wm*64 + m*16 + lr, kk);
    STAGEA(t + 2, 0);
    __builtin_amdgcn_s_barrier();
    asm volatile("s_waitcnt lgkmcnt(0)" ::: "memory");
    __builtin_amdgcn_sched_barrier(0);
    __builtin_amdgcn_s_setprio(1);
#pragma unroll
    for (int m = 0; m < 4; ++m)
#pragma unroll
      for (int nn = 0; nn < 2; ++nn)
#pragma unroll
        for (int kk = 0; kk < 2; ++kk)
          acc[4+m][2+nn] = __builtin_amdgcn_mfma_f32_16x16x32_bf16(a[m][kk], b[nn][kk], acc[4+m][2+nn], 0, 0, 0);
    __builtin_amdgcn_s_setprio(0);
    __builtin_amdgcn_sched_barrier(0);
    __builtin_amdgcn_s_barrier();
    // ---------- q3: no ds_reads (A1 + held B0); cvt+write B1(t+1); issue B1(t+2) ----------
    asm volatile("s_waitcnt vmcnt(8)" ::: "memory");   // B1(t+1) regs ready (A0(t+1) also drained)
    CVTW(rB1, d ^ 1, 1);
    LOADB(rB1, t + 2, 1);
    __builtin_amdgcn_s_barrier();
    asm volatile("s_waitcnt lgkmcnt(0)" ::: "memory");
    __builtin_amdgcn_sched_barrier(0);
    __builtin_amdgcn_s_setprio(1);
#pragma unroll
    for (int m = 0; m < 4; ++m)
#pragma unroll
      for (int nn = 0; nn < 2; ++nn)
#pragma unroll
        for (int kk = 0; kk < 2; ++kk)
          acc[4+m][nn] = __builtin_amdgcn_mfma_f32_16x16x32_bf16(a[m][kk], b0h[nn][kk], acc[4+m][nn], 0, 0, 0);
    __builtin_amdgcn_s_setprio(0);
    __builtin_amdgcn_sched_barrier(0);
    asm volatile("s_waitcnt vmcnt(10)" ::: "memory");  // K-tile boundary: A1(t+1) landed
    __builtin_amdgcn_s_barrier();
  }

  // epilogue: C/D map col=lane&15, row=(lane>>4)*4+reg  [verified m89]
  const int rl = (lane >> 4) << 2;
  if (ACT) {
#pragma unroll
    for (int mq = 0; mq < 2; ++mq)
#pragma unroll
      for (int m = 0; m < 4; ++m) {
        int rbase = mq*128 + wm*64 + m*16 + rl;
#pragma unroll
        for (int nq = 0; nq < 2; ++nq) {
          f32x4 h1 = acc[mq*4+m][nq*2], h3 = acc[mq*4+m][nq*2+1];
          int ucol = xt*128 + nq*64 + wn*16 + lr;
#pragma unroll
          for (int j = 0; j < 4; ++j) {
            int lrow = rbase + j;
            if (lrow < rv) {
              float v1 = h1[j];
              float uu = v1 / (1.f + __expf(-v1)) * h3[j];   // silu(h1)*h3
              out[(size_t)(rowbase + brow + lrow) * IDIM + ucol] = f32_to_bf16(uu);
            }
          }
        }
      }
  } else {
#pragma unroll
    for (int mq = 0; mq < 2; ++mq)
#pragma unroll
      for (int m = 0; m < 4; ++m) {
        int rbase = mq*128 + wm*64 + m*16 + rl;
#pragma unroll
        for (int nq = 0; nq < 2; ++nq)
#pragma unroll
          for (int nn = 0; nn < 2; ++nn) {
            int col = xt*256 + nq*128 + wn*32 + nn*16 + lr;
            f32x4 v = acc[mq*4+m][nq*2+nn];
#pragma unroll
            for (int j = 0; j < 4; ++j) {
              int lrow = rbase + j;
              if (lrow < rv)
                out[(size_t)(rowbase + brow + lrow) * HDIM + col] = f32_to_bf16(v[j]);
            }
          }
      }
  }
}

// ---------------- combine: y[t] = sum_k w_k * oe[e_k][pos_k] + shared[t] ----------------
__global__ __launch_bounds__(256) void k_combine(const u16* __restrict__ oe,
                                                 const int* __restrict__ idx, const float* __restrict__ wts,
                                                 const int* __restrict__ pos, float* __restrict__ y) {
  int t = blockIdx.x;
  int h0 = threadIdx.x * 4;
  float a0 = 0, a1 = 0, a2 = 0, a3 = 0;
#pragma unroll
  for (int k = 0; k < KSEL; ++k) {
    int e = idx[t*KSEL + k];
    int p = pos[t*KSEL + k];
    if (p < CAPE) {
      float w = wts[t*KSEL + k];
      ushort4 v = *reinterpret_cast<const ushort4*>(oe + ((long)e * CAPE + p) * HDIM + h0);
      a0 += w * bf16_to_f32(v.x); a1 += w * bf16_to_f32(v.y);
      a2 += w * bf16_to_f32(v.z); a3 += w * bf16_to_f32(v.w);
    }
  }
  ushort4 s = *reinterpret_cast<const ushort4*>(oe + ((long)NEXP * CAPE + t) * HDIM + h0);
  a0 += bf16_to_f32(s.x); a1 += bf16_to_f32(s.y); a2 += bf16_to_f32(s.z); a3 += bf16_to_f32(s.w);
  float4 o2; o2.x = a0; o2.y = a1; o2.z = a2; o2.w = a3;
  reinterpret_cast<float4*>(y + (long)t * HDIM)[threadIdx.x] = o2;
}

extern "C" void kernel_launch(void* const* d_in, const int* in_sizes, int n_in,
                              void* d_out, int out_size, void* d_ws, size_t ws_size,
                              hipStream_t stream) {
  const float* x      = (const float*)d_in[0];
  const float* gate_w = (const float*)d_in[1];
  const float* w13    = (const float*)d_in[2];
  const float* w2     = (const float*)d_in[3];
  const float* sw1    = (const float*)d_in[4];
  const float* sw2    = (const float*)d_in[5];
  const float* sw3    = (const float*)d_in[6];
  float* y = (float*)d_out;

  char* base = (char*)d_ws;
  size_t off = 0;
  auto alloc = [&](size_t bytes) -> void* {
    void* p = base + off;
    off = (off + bytes + 255) & ~(size_t)255;
    return p;
  };
  u16* xb    = (u16*)alloc((size_t)T_TOK * HDIM * 2);
  u16* u_ws  = (u16*)alloc((size_t)NROW * IDIM * 2);
  u16* oe_ws = (u16*)alloc((size_t)NROW * HDIM * 2);
  int*   idx  = (int*)alloc((size_t)T_TOK * KSEL * 4);
  float* wts  = (float*)alloc((size_t)T_TOK * KSEL * 4);
  int*   pos  = (int*)alloc((size_t)T_TOK * KSEL * 4);
  int*   etok = (int*)alloc((size_t)NROW * 4);
  int*   cnts = (int*)alloc(256);
  int*   list = (int*)alloc(MAXTILE * 4);
  int*   tot  = (int*)alloc(64);
  int*   done = (int*)alloc(64);
  if (off > ws_size) return;

  k_gate<<<dim3(T_TOK / 32), dim3(256), 0, stream>>>(x, gate_w, idx, wts, xb, done);
  k_assign<<<dim3(NEXP + 1), dim3(1024), 0, stream>>>(idx, etok, pos, cnts, list, tot, done);

  // GEMM1: A=xb gathered, B=w13 fp32 (w1/w3 interleave), silu*mul epilogue -> u_ws
  k_gemm8<HDIM, true,  true,  true ><<<dim3(MAXWG), dim3(512), 0, stream>>>(
      xb, w13, sw1, sw3, u_ws, etok, cnts, list, tot);
  // GEMM2: A=u_ws dense, B=w2 fp32 -> oe_ws
  k_gemm8<IDIM, false, false, false><<<dim3(MAXWG), dim3(512), 0, stream>>>(
      u_ws, w2, sw2, nullptr, oe_ws, etok, cnts, list, tot);

  k_combine<<<dim3(T_TOK), dim3(256), 0, stream>>>(oe_ws, idx, wts, pos, y);
}

// Round 5
// 271.023 us; speedup vs baseline: 1.3983x; 1.1771x over previous
//
#include <hip/hip_runtime.h>

typedef unsigned short u16;
typedef unsigned int u32;
typedef float f32x4 __attribute__((ext_vector_type(4)));
typedef __bf16 bf16x8 __attribute__((ext_vector_type(8)));

#define T_TOK 4096
#define HDIM 1024
#define IDIM 512
#define NEXP 32
#define KSEL 8
#define CAPE 2048
#define NROW (NEXP*CAPE + T_TOK)   // 69632 rows total (experts + shared)
#define MAXTILE 528                // 33 experts * 16 y-tiles max
#define MAXWG  (MAXTILE*4)         // 2112
#define CVTWG  512                 // guaranteed converter blocks appended to GEMM1

__device__ __forceinline__ u16 f32_to_bf16(float f) {
  u32 x = __float_as_uint(f);
  u32 r = (x + 0x7FFFu + ((x >> 16) & 1u)) >> 16;   // RNE; inputs finite
  return (u16)r;
}
__device__ __forceinline__ float bf16_to_f32(u16 u) {
  return __uint_as_float(((u32)u) << 16);
}

// ---------------- k_pre: gate (blocks 0..127) ∪ w13 interleave convert (blocks 128..2175) ----------------
// Gate: fp64 logits, group-limited top-k on logits (sigmoid monotonic), sigmoid only for the 8
// winners; fused x->bf16. Convert: w13 (+sw1/sw3 as expert 32) -> bf16 with 16-row w1/w3 interleave.
__global__ __launch_bounds__(256) void k_pre(const float* __restrict__ x, const float* __restrict__ gw,
                                             const float* __restrict__ w13,
                                             const float* __restrict__ sw1, const float* __restrict__ sw3,
                                             int* __restrict__ idx, float* __restrict__ wts,
                                             u16* __restrict__ xb, u16* __restrict__ w13b,
                                             int* __restrict__ done) {
  const int tid = threadIdx.x;
  if (blockIdx.x >= 128) {
    // ---- w13 convert: chunk j of 8 f32; dest row rd: c=rd>>4, even c -> w1 rows (c>>1)*16.., odd -> w3
    const long n8 = (long)(NEXP + 1) * 1024 * 128;
    const long stride = (long)(2176 - 128) * 256;
    for (long j = (long)(blockIdx.x - 128) * 256 + tid; j < n8; j += stride) {
      int e   = (int)(j >> 17);
      int rem = (int)(j & 131071);
      int rowd = rem >> 7;
      int c8   = rem & 127;
      int c = rowd >> 4, cw = rowd & 15;
      int srow = (c >> 1) * 16 + cw;
      int sel = c & 1;
      const float* s;
      if (e < NEXP) s = w13 + (size_t)e * (2 * IDIM * HDIM) + (size_t)(sel * IDIM + srow) * HDIM + c8 * 8;
      else          s = (sel ? sw3 : sw1) + (size_t)srow * HDIM + c8 * 8;
      float4 a = reinterpret_cast<const float4*>(s)[0];
      float4 b = reinterpret_cast<const float4*>(s)[1];
      ushort4 lo, hi;
      lo.x=f32_to_bf16(a.x); lo.y=f32_to_bf16(a.y); lo.z=f32_to_bf16(a.z); lo.w=f32_to_bf16(a.w);
      hi.x=f32_to_bf16(b.x); hi.y=f32_to_bf16(b.y); hi.z=f32_to_bf16(b.z); hi.w=f32_to_bf16(b.w);
      u16* d = w13b + ((size_t)e * 1024 + rowd) * HDIM + c8 * 8;
      reinterpret_cast<ushort4*>(d)[0] = lo;
      reinterpret_cast<ushort4*>(d)[1] = hi;
    }
    return;
  }
  // ---- gate path ----
  __shared__ float xs[32][129];
  __shared__ float gs_[32][129];
  __shared__ double sc[32][32];
  const int t0 = blockIdx.x * 32;
  const int tl = tid & 31, g = tid >> 5;
  if (blockIdx.x == 0 && tid == 0) done[0] = 0;   // reset rendezvous for k_assign (next launch)
  double acc0 = 0, acc1 = 0, acc2 = 0, acc3 = 0;
  for (int k0 = 0; k0 < HDIM; k0 += 128) {
#pragma unroll
    for (int q = 0; q < 4; ++q) {
      int f = tid + 256 * q;
      int row = f >> 5, c4 = (f & 31) * 4;
      float4 v = *reinterpret_cast<const float4*>(x + (long)(t0 + row) * HDIM + k0 + c4);
      xs[row][c4+0]=v.x; xs[row][c4+1]=v.y; xs[row][c4+2]=v.z; xs[row][c4+3]=v.w;
      ushort4 xv; xv.x=f32_to_bf16(v.x); xv.y=f32_to_bf16(v.y); xv.z=f32_to_bf16(v.z); xv.w=f32_to_bf16(v.w);
      *reinterpret_cast<ushort4*>(xb + (long)(t0 + row) * HDIM + k0 + c4) = xv;   // fused x convert
      float4 w = *reinterpret_cast<const float4*>(gw + (long)row * HDIM + k0 + c4);
      gs_[row][c4+0]=w.x; gs_[row][c4+1]=w.y; gs_[row][c4+2]=w.z; gs_[row][c4+3]=w.w;
    }
    __syncthreads();
#pragma unroll 4
    for (int kk = 0; kk < 128; ++kk) {
      double xv = (double)xs[tl][kk];
      acc0 += xv * (double)gs_[g     ][kk];
      acc1 += xv * (double)gs_[g +  8][kk];
      acc2 += xv * (double)gs_[g + 16][kk];
      acc3 += xv * (double)gs_[g + 24][kk];
    }
    __syncthreads();
  }
  sc[tl][g     ] = acc0;   // raw logits
  sc[tl][g +  8] = acc1;
  sc[tl][g + 16] = acc2;
  sc[tl][g + 24] = acc3;
  __syncthreads();
  if (tid < 32) {
    int t = t0 + tid;
    double gsc[8];
#pragma unroll
    for (int gg = 0; gg < 8; ++gg) {
      double mx = sc[tid][4*gg];
#pragma unroll
      for (int j = 1; j < 4; ++j) mx = fmax(mx, sc[tid][4*gg + j]);
      gsc[gg] = mx;
    }
    unsigned gmask = 0;
    for (int it = 0; it < 4; ++it) {          // top-4 groups, strict >, first index wins
      double best = -1e300; int bi = 0;
      for (int gg = 0; gg < 8; ++gg)
        if (!((gmask >> gg) & 1) && gsc[gg] > best) { best = gsc[gg]; bi = gg; }
      gmask |= 1u << bi;
    }
    unsigned emask = 0; int ei[KSEL]; double ew[KSEL]; double wsum = 0;
    for (int it = 0; it < KSEL; ++it) {       // top-8 experts on logits
      double best = -1e300; int bi = 0;
      for (int e = 0; e < NEXP; ++e)
        if (((gmask >> (e >> 2)) & 1) && !((emask >> e) & 1)) {
          double v = sc[tid][e];
          if (v > best) { best = v; bi = e; }
        }
      emask |= 1u << bi; ei[it] = bi;
      double sg = 1.0 / (1.0 + exp(-best));   // sigmoid only for selected
      ew[it] = sg; wsum += sg;
    }
    double s = 2.5 / (wsum + 1e-20);
    for (int k = 0; k < KSEL; ++k) { idx[t*KSEL + k] = ei[k]; wts[t*KSEL + k] = (float)(ew[k] * s); }
  }
}

// ---------------- capacity assignment (ballot-scan) + inline tile scheduler ----------------
__global__ __launch_bounds__(1024) void k_assign(const int* __restrict__ idx,
                                                 int* __restrict__ etok, int* __restrict__ pos,
                                                 int* __restrict__ cnts,
                                                 int* __restrict__ list, int* __restrict__ tot,
                                                 int* __restrict__ done) {
  const int e = blockIdx.x;
  const int tid = threadIdx.x;
  int base = 0;
  if (e == NEXP) {                             // shared "expert": identity token list
    for (int t = tid; t < T_TOK; t += 1024) etok[NEXP*CAPE + t] = t;
    base = T_TOK;
  } else {
    __shared__ int wbase[17];
    const int wid = tid >> 6, lane = tid & 63;
    for (int c = 0; c < T_TOK / 1024; ++c) {
      int t = c * 1024 + tid;
      int found = -1;
#pragma unroll
      for (int k = 0; k < KSEL; ++k) if (idx[t*KSEL + k] == e) found = k;
      unsigned long long mask = __ballot(found >= 0);
      int myrank = __popcll(mask & ((1ull << lane) - 1ull));
      __syncthreads();
      if (lane == 0) wbase[wid] = __popcll(mask);
      __syncthreads();
      if (tid == 0) {
        int run = 0;
#pragma unroll
        for (int w = 0; w < 16; ++w) { int v = wbase[w]; wbase[w] = run; run += v; }
        wbase[16] = run;
      }
      __syncthreads();
      if (found >= 0) {
        int slot = base + wbase[wid] + myrank;
        pos[t*KSEL + found] = slot;
        if (slot < CAPE) etok[e*CAPE + slot] = t;
      }
      base += wbase[16];
      __syncthreads();
    }
    base = min(base, CAPE);
  }
  if (tid == 0) {
    cnts[e] = base;
    __threadfence();
    if (atomicAdd(done, 1) == NEXP) {          // last finisher builds the compact work list
      __threadfence();
      int run = 0;
      for (int ee = 0; ee <= NEXP; ++ee) {
        int c = atomicAdd(&cnts[ee], 0);       // device-scope read
        int nt = (c + 255) >> 8;
        for (int i = 0; i < nt; ++i) list[run + i] = ee * 16 + i;
        run += nt;
      }
      tot[0] = run * 4;
    }
  }
}

// ---------------- grouped GEMM: 256x256 tile, BK=64, 8-phase counted-vmcnt schedule ----------------
// r3-proven inner loop: T1 bijective XCD swizzle over active prefix + T2 XOR LDS swizzle +
// T3/T4 8-phase counted vmcnt(6) + T5 setprio. Blocks beyond the active prefix run the
// fp32->bf16 converter for the NEXT GEMM's B (w2/sw2) instead of exiting (cvt_n8>0 only on GEMM1).

#define GLDS(gp, lp) __builtin_amdgcn_global_load_lds( \
    (const __attribute__((address_space(1))) void*)(gp), \
    (__attribute__((address_space(3))) void*)(lp), 16, 0, 0)

template<int KDIM, bool GATHER, bool ACT>
__global__ __launch_bounds__(512, 2) void k_gemm8(const u16* __restrict__ A, const u16* __restrict__ Ball,
                                                  u16* __restrict__ out,
                                                  const int* __restrict__ etok, const int* __restrict__ cnts,
                                                  const int* __restrict__ list, const int* __restrict__ tot,
                                                  const float* __restrict__ cvsrc, const float* __restrict__ cvsrc2,
                                                  u16* __restrict__ cvdst, long cvt_n8) {
  constexpr int NT = KDIM / 64;
  constexpr int MSK = NT - 1;
  __shared__ u16 lds[65536];            // [dbuf 2][op 2][256*64], 128 KiB

  const int n = tot[0];                 // active wg count (4 * tiles)
  const int bid0 = blockIdx.x;
  const int tid = threadIdx.x;
  if (bid0 >= n) {
    // ---- converter service: stream cvsrc (E experts) + cvsrc2 (shared) -> cvdst bf16 ----
    if (cvt_n8 > 0) {
      const long nb = (long)gridDim.x - n;
      const long stride = nb * 512;
      for (long j = (long)(bid0 - n) * 512 + tid; j < cvt_n8; j += stride) {
        int e   = (int)(j >> 16);                    // 65536 chunks per expert (H*I/8)
        int rem = (int)(j & 65535);
        const float* s = ((e < NEXP) ? cvsrc + ((size_t)e << 19) : cvsrc2) + (size_t)rem * 8;
        float4 a = reinterpret_cast<const float4*>(s)[0];
        float4 b = reinterpret_cast<const float4*>(s)[1];
        ushort4 lo, hi;
        lo.x=f32_to_bf16(a.x); lo.y=f32_to_bf16(a.y); lo.z=f32_to_bf16(a.z); lo.w=f32_to_bf16(a.w);
        hi.x=f32_to_bf16(b.x); hi.y=f32_to_bf16(b.y); hi.z=f32_to_bf16(b.z); hi.w=f32_to_bf16(b.w);
        u16* d = cvdst + ((size_t)e << 19) + (size_t)rem * 8;
        reinterpret_cast<ushort4*>(d)[0] = lo;
        reinterpret_cast<ushort4*>(d)[1] = hi;
      }
    }
    return;
  }
  // m204 bijective XCD swizzle over [0,n)
  const int q = n >> 3, r = n & 7, xc = bid0 & 7, o = bid0 >> 3;
  const int wg = (xc < r ? xc * (q + 1) : r * (q + 1) + (xc - r) * q) + o;
  const int item = list[wg >> 2];
  const int e = item >> 4, yt = item & 15, xt = wg & 3;

  const int cnt = cnts[e];
  const int brow = yt * 256;
  const int rv = min(256, cnt - brow);
  const long rowbase = (long)e * CAPE;
  const u16* Bexp = Ball + (size_t)e * (size_t)(1024 * KDIM);

  const int wave = tid >> 6, lane = tid & 63;
  const int wm = wave >> 2, wn = wave & 3;
  const int lr = lane & 15;
  const int lk = (lane >> 4) * 16;      // byte offset of this lane's K-slot

  // staging source pointers: sub-issue j covers tile rows j*64..j*64+63
  const u16* pa[4]; const u16* pb[4];
#pragma unroll
  for (int j = 0; j < 4; ++j) {
    int row = j*64 + (tid >> 3);
    int sl = (tid & 7) ^ (row & 7);                  // pre-swizzled source chunk
    long arow;
    if (GATHER) arow = (row < rv) ? (long)etok[rowbase + brow + row] : 0L;
    else        arow = rowbase + brow + row;
    pa[j] = A + arow * KDIM + sl * 8;
    pb[j] = Bexp + ((long)(xt*256 + row)) * KDIM + sl * 8;
  }

  // stage half h (0: rows 0-127, 1: rows 128-255) of operand op of K-tile st
  auto STAGE = [&](int st, int op, int h) {
    int dbase = (st & 1) * 32768 + op * 16384;
    const u16* const* pp = op ? pb : pa;
#pragma unroll
    for (int s = 0; s < 2; ++s) {
      int j = h*2 + s;
      GLDS(pp[j] + st * 64, &lds[dbase + j*4096 + wave*512]);
    }
  };

  const char* ldsb = (const char*)lds;
  auto RD = [&](int d, int op, int rr, int kk) -> bf16x8 {
    int bc = (kk*64 + lk) ^ ((rr & 7) << 4);
    return *(const bf16x8*)(ldsb + (size_t)(d*65536 + op*32768 + rr*128 + bc));
  };

  f32x4 acc[8][4];
#pragma unroll
  for (int m = 0; m < 8; ++m)
#pragma unroll
    for (int nn = 0; nn < 4; ++nn) acc[m][nn] = (f32x4){0.f,0.f,0.f,0.f};

  // prologue: tile0 fully, tile1 {A0,B0,B1}; A1(1) staged at t=0.q0
  STAGE(0,0,0); STAGE(0,1,0); STAGE(0,0,1); STAGE(0,1,1);
  STAGE(1,0,0); STAGE(1,1,0); STAGE(1,1,1);
  asm volatile("s_waitcnt vmcnt(6)" ::: "memory");    // tile0's 8 loads landed
  __builtin_amdgcn_sched_barrier(0);
  __builtin_amdgcn_s_barrier();

  bf16x8 a[4][2], b[2][2], b0h[2][2];

  for (int t = 0; t < NT; ++t) {
    const int d = t & 1;
    // ---------- q0: (mq=0,nq=0) — read A0(8)+B0(4); stage A1(t+1) ----------
#pragma unroll
    for (int m = 0; m < 4; ++m)
#pragma unroll
      for (int kk = 0; kk < 2; ++kk) a[m][kk] = RD(d, 0, wm*64 + m*16 + lr, kk);
#pragma unroll
    for (int nn = 0; nn < 2; ++nn)
#pragma unroll
      for (int kk = 0; kk < 2; ++kk) { b[nn][kk] = RD(d, 1, wn*32 + nn*16 + lr, kk); b0h[nn][kk] = b[nn][kk]; }
    STAGE((t+1) & MSK, 0, 1);
    __builtin_amdgcn_s_barrier();
    asm volatile("s_waitcnt lgkmcnt(0)" ::: "memory");
    __builtin_amdgcn_sched_barrier(0);
    __builtin_amdgcn_s_setprio(1);
#pragma unroll
    for (int m = 0; m < 4; ++m)
#pragma unroll
      for (int nn = 0; nn < 2; ++nn)
#pragma unroll
        for (int kk = 0; kk < 2; ++kk)
          acc[m][nn] = __builtin_amdgcn_mfma_f32_16x16x32_bf16(a[m][kk], b[nn][kk], acc[m][nn], 0, 0, 0);
    __builtin_amdgcn_s_setprio(0);
    __builtin_amdgcn_sched_barrier(0);
    __builtin_amdgcn_s_barrier();
    // ---------- q1: (mq=0,nq=1) — read B1(4); stage B0(t+2) ----------
#pragma unroll
    for (int nn = 0; nn < 2; ++nn)
#pragma unroll
      for (int kk = 0; kk < 2; ++kk) b[nn][kk] = RD(d, 1, 128 + wn*32 + nn*16 + lr, kk);
    STAGE((t+2) & MSK, 1, 0);
    __builtin_amdgcn_s_barrier();
    asm volatile("s_waitcnt lgkmcnt(0)" ::: "memory");
    __builtin_amdgcn_sched_barrier(0);
    __builtin_amdgcn_s_setprio(1);
#pragma unroll
    for (int m = 0; m < 4; ++m)
#pragma unroll
      for (int nn = 0; nn < 2; ++nn)
#pragma unroll
        for (int kk = 0; kk < 2; ++kk)
          acc[m][2+nn] = __builtin_amdgcn_mfma_f32_16x16x32_bf16(a[m][kk], b[nn][kk], acc[m][2+nn], 0, 0, 0);
    __builtin_amdgcn_s_setprio(0);
    __builtin_amdgcn_sched_barrier(0);
    __builtin_amdgcn_s_barrier();
    // ---------- q2: (mq=1,nq=1) — read A1(8); stage A0(t+2) ----------
#pragma unroll
    for (int m = 0; m < 4; ++m)
#pragma unroll
      for (int kk = 0; kk < 2; ++kk) a[m][kk] = RD(d, 0, 128 + wm*64 + m*16 + lr, kk);
    STAGE((t+2) & MSK, 0, 0);
    __builtin_amdgcn_s_barrier();
    asm volatile("s_waitcnt lgkmcnt(0)" ::: "memory");
    __builtin_amdgcn_sched_barrier(0);
    __builtin_amdgcn_s_setprio(1);
#pragma unroll
    for (int m = 0; m < 4; ++m)
#pragma unroll
      for (int nn = 0; nn < 2; ++nn)
#pragma unroll
        for (int kk = 0; kk < 2; ++kk)
          acc[4+m][2+nn] = __builtin_amdgcn_mfma_f32_16x16x32_bf16(a[m][kk], b[nn][kk], acc[4+m][2+nn], 0, 0, 0);
    __builtin_amdgcn_s_setprio(0);
    __builtin_amdgcn_sched_barrier(0);
    __builtin_amdgcn_s_barrier();
    // ---------- q3: (mq=1,nq=0) — no ds_reads (A1 + held B0); stage B1(t+2) ----------
    STAGE((t+2) & MSK, 1, 1);
    __builtin_amdgcn_s_barrier();
    asm volatile("s_waitcnt lgkmcnt(0)" ::: "memory");
    __builtin_amdgcn_sched_barrier(0);
    __builtin_amdgcn_s_setprio(1);
#pragma unroll
    for (int m = 0; m < 4; ++m)
#pragma unroll
      for (int nn = 0; nn < 2; ++nn)
#pragma unroll
        for (int kk = 0; kk < 2; ++kk)
          acc[4+m][nn] = __builtin_amdgcn_mfma_f32_16x16x32_bf16(a[m][kk], b0h[nn][kk], acc[4+m][nn], 0, 0, 0);
    __builtin_amdgcn_s_setprio(0);
    __builtin_amdgcn_sched_barrier(0);
    asm volatile("s_waitcnt vmcnt(6)" ::: "memory");    // K-tile boundary: tile t+1 fully landed
    __builtin_amdgcn_s_barrier();
  }

  // epilogue: C/D map col=lane&15, row=(lane>>4)*4+reg  [verified m89]
  const int rl = (lane >> 4) << 2;
  if (ACT) {
#pragma unroll
    for (int mq = 0; mq < 2; ++mq)
#pragma unroll
      for (int m = 0; m < 4; ++m) {
        int rbase = mq*128 + wm*64 + m*16 + rl;
#pragma unroll
        for (int nq = 0; nq < 2; ++nq) {
          f32x4 h1 = acc[mq*4+m][nq*2], h3 = acc[mq*4+m][nq*2+1];
          int ucol = xt*128 + nq*64 + wn*16 + lr;
#pragma unroll
          for (int j = 0; j < 4; ++j) {
            int lrow = rbase + j;
            if (lrow < rv) {
              float v1 = h1[j];
              float uu = v1 / (1.f + __expf(-v1)) * h3[j];   // silu(h1)*h3
              out[(size_t)(rowbase + brow + lrow) * IDIM + ucol] = f32_to_bf16(uu);
            }
          }
        }
      }
  } else {
#pragma unroll
    for (int mq = 0; mq < 2; ++mq)
#pragma unroll
      for (int m = 0; m < 4; ++m) {
        int rbase = mq*128 + wm*64 + m*16 + rl;
#pragma unroll
        for (int nq = 0; nq < 2; ++nq)
#pragma unroll
          for (int nn = 0; nn < 2; ++nn) {
            int col = xt*256 + nq*128 + wn*32 + nn*16 + lr;
            f32x4 v = acc[mq*4+m][nq*2+nn];
#pragma unroll
            for (int j = 0; j < 4; ++j) {
              int lrow = rbase + j;
              if (lrow < rv)
                out[(size_t)(rowbase + brow + lrow) * HDIM + col] = f32_to_bf16(v[j]);
            }
          }
      }
  }
}

// ---------------- combine: y[t] = sum_k w_k * oe[e_k][pos_k] + shared[t] ----------------
__global__ __launch_bounds__(256) void k_combine(const u16* __restrict__ oe,
                                                 const int* __restrict__ idx, const float* __restrict__ wts,
                                                 const int* __restrict__ pos, float* __restrict__ y) {
  int t = blockIdx.x;
  int h0 = threadIdx.x * 4;
  float a0 = 0, a1 = 0, a2 = 0, a3 = 0;
#pragma unroll
  for (int k = 0; k < KSEL; ++k) {
    int e = idx[t*KSEL + k];
    int p = pos[t*KSEL + k];
    if (p < CAPE) {
      float w = wts[t*KSEL + k];
      ushort4 v = *reinterpret_cast<const ushort4*>(oe + ((long)e * CAPE + p) * HDIM + h0);
      a0 += w * bf16_to_f32(v.x); a1 += w * bf16_to_f32(v.y);
      a2 += w * bf16_to_f32(v.z); a3 += w * bf16_to_f32(v.w);
    }
  }
  ushort4 s = *reinterpret_cast<const ushort4*>(oe + ((long)NEXP * CAPE + t) * HDIM + h0);
  a0 += bf16_to_f32(s.x); a1 += bf16_to_f32(s.y); a2 += bf16_to_f32(s.z); a3 += bf16_to_f32(s.w);
  float4 o2; o2.x = a0; o2.y = a1; o2.z = a2; o2.w = a3;
  reinterpret_cast<float4*>(y + (long)t * HDIM)[threadIdx.x] = o2;
}

extern "C" void kernel_launch(void* const* d_in, const int* in_sizes, int n_in,
                              void* d_out, int out_size, void* d_ws, size_t ws_size,
                              hipStream_t stream) {
  const float* x      = (const float*)d_in[0];
  const float* gate_w = (const float*)d_in[1];
  const float* w13    = (const float*)d_in[2];
  const float* w2     = (const float*)d_in[3];
  const float* sw1    = (const float*)d_in[4];
  const float* sw2    = (const float*)d_in[5];
  const float* sw3    = (const float*)d_in[6];
  float* y = (float*)d_out;

  char* base = (char*)d_ws;
  size_t off = 0;
  auto alloc = [&](size_t bytes) -> void* {
    void* p = base + off;
    off = (off + bytes + 255) & ~(size_t)255;
    return p;
  };
  u16* xb    = (u16*)alloc((size_t)T_TOK * HDIM * 2);
  u16* w13b  = (u16*)alloc((size_t)(NEXP + 1) * 2 * IDIM * HDIM * 2);
  u16* w2b   = (u16*)alloc((size_t)(NEXP + 1) * HDIM * IDIM * 2);
  u16* u_ws  = (u16*)alloc((size_t)NROW * IDIM * 2);
  u16* oe_ws = (u16*)alloc((size_t)NROW * HDIM * 2);
  int*   idx  = (int*)alloc((size_t)T_TOK * KSEL * 4);
  float* wts  = (float*)alloc((size_t)T_TOK * KSEL * 4);
  int*   pos  = (int*)alloc((size_t)T_TOK * KSEL * 4);
  int*   etok = (int*)alloc((size_t)NROW * 4);
  int*   cnts = (int*)alloc(256);
  int*   list = (int*)alloc(MAXTILE * 4);
  int*   tot  = (int*)alloc(64);
  int*   done = (int*)alloc(64);
  if (off > ws_size) return;

  // 1. gate (128 blocks) || w13+sw1/sw3 -> bf16 interleave convert (2048 blocks)
  k_pre<<<dim3(2176), dim3(256), 0, stream>>>(x, gate_w, w13, sw1, sw3, idx, wts, xb, w13b, done);
  // 2. capacity assignment + inline work-list scheduler
  k_assign<<<dim3(NEXP + 1), dim3(1024), 0, stream>>>(idx, etok, pos, cnts, list, tot, done);
  // 3. GEMM1 (bf16 w13b); inactive blocks convert w2+sw2 -> w2b in GEMM1's shadow
  k_gemm8<HDIM, true,  true ><<<dim3(MAXWG + CVTWG), dim3(512), 0, stream>>>(
      xb, w13b, u_ws, etok, cnts, list, tot,
      w2, sw2, w2b, (long)(NEXP + 1) * HDIM * IDIM / 8);
  // 4. GEMM2 (bf16 w2b)
  k_gemm8<IDIM, false, false><<<dim3(MAXWG), dim3(512), 0, stream>>>(
      u_ws, w2b, oe_ws, etok, cnts, list, tot,
      nullptr, nullptr, nullptr, 0L);
  // 5. combine
  k_combine<<<dim3(T_TOK), dim3(256), 0, stream>>>(oe_ws, idx, wts, pos, y);
}